// Round 1
// baseline (1460.132 us; speedup 1.0000x reference)
//
#include <hip/hip_runtime.h>
#include <hip/hip_bf16.h>

// SplineConv (degree-1 B-spline, DIM=2, K=5, open), N=100000, E=1600000, 32->32.
// R8: factor the computation like the reference does: per-edge work is ONLY the
//     scatter h[row][k][i] += b_s * x_j[i] (16 ds_add_f32 + 16 mul per lane,
//     teams of 8), then one 32x800x32 GEMM per 32-row block done with MFMA
//     (bf16 h x bf16 W, fp32 accum). This removes R7's per-edge 32x32
//     weight-combine (~9.2K VALU lane-ops + 512 LDS b128 lane-reads per edge)
//     which modeled to ~440us of pipe time. h tile fp32 in LDS, k-pitch 33
//     (odd -> ds_add banks spread); W staged per block in MFMA B-fragment
//     order (bf16, 51.2KB); edges interleaved across 128 teams so same-wave
//     teams sit on different rows (no same-address LDS atomic serialization).
//     scan2 upgraded from 1-thread serial to a 128-lane block scan.

#define NN   100000
#define EE   1600000
#define KTOT 25

#define ROWS_PB 32
#define NBLK    (NN / ROWS_PB)        // 3125 exact, no tail
#define HP      33                    // dword pitch per k-slot (odd: bank spread)
#define HROW    (KTOT * HP)           // 825 dwords per row
#define TEAMS   128                   // 1024 threads / 8 lanes per team

// ws layout (int32 units): counts | offsets | cursor | blksum | sorted
#define WS_COUNTS  0
#define WS_OFFSETS 100000
#define WS_CURSOR  200000
#define WS_BLKSUM  300000
#define WS_SORTED  300128
#define SCAN_NBLK  98                 // ceil(100000/1024)

typedef __attribute__((ext_vector_type(8))) short short8;
typedef __attribute__((ext_vector_type(4))) float f32x4;

__global__ void hist_kernel(const int* __restrict__ eidx, int* __restrict__ counts) {
    for (int e = blockIdx.x * blockDim.x + threadIdx.x; e < EE; e += gridDim.x * blockDim.x)
        atomicAdd(&counts[eidx[e]], 1);
}

__global__ __launch_bounds__(1024)
void scan1_kernel(const int* __restrict__ counts, int* __restrict__ offsets,
                  int* __restrict__ blksum) {
    __shared__ int buf[2][1024];
    int tid = threadIdx.x;
    int gid = blockIdx.x * 1024 + tid;
    int v = (gid < NN) ? counts[gid] : 0;
    buf[0][tid] = v;
    __syncthreads();
    int s = 0;
    for (int off = 1; off < 1024; off <<= 1) {
        int t = buf[s][tid];
        if (tid >= off) t += buf[s][tid - off];
        buf[1 - s][tid] = t;
        s ^= 1;
        __syncthreads();
    }
    if (gid < NN) offsets[gid] = buf[s][tid] - v;      // exclusive
    if (tid == 1023) blksum[blockIdx.x] = buf[s][tid]; // block total
}

__global__ __launch_bounds__(128)
void scan2_kernel(int* __restrict__ blksum) {
    __shared__ int buf[2][128];
    int tid = threadIdx.x;
    int v = (tid < SCAN_NBLK) ? blksum[tid] : 0;
    buf[0][tid] = v;
    __syncthreads();
    int s = 0;
    for (int off = 1; off < 128; off <<= 1) {
        int t = buf[s][tid];
        if (tid >= off) t += buf[s][tid - off];
        buf[1 - s][tid] = t;
        s ^= 1;
        __syncthreads();
    }
    if (tid < SCAN_NBLK) blksum[tid] = buf[s][tid] - v; // exclusive
}

__global__ __launch_bounds__(1024)
void scan3_kernel(int* __restrict__ offsets, const int* __restrict__ blksum,
                  int* __restrict__ cursor) {
    int gid = blockIdx.x * 1024 + threadIdx.x;
    if (gid < NN) {
        int o = offsets[gid] + blksum[blockIdx.x];
        offsets[gid] = o;
        cursor[gid] = o;
    }
}

__global__ void scatter_kernel(const int* __restrict__ eidx, int* __restrict__ cursor,
                               int* __restrict__ sorted) {
    for (int e = blockIdx.x * blockDim.x + threadIdx.x; e < EE; e += gridDim.x * blockDim.x) {
        int pos = atomicAdd(&cursor[eidx[e]], 1);
        sorted[pos] = e;
    }
}

__global__ __launch_bounds__(1024)
void block_kernel(const float* __restrict__ x,
                  const int* __restrict__ eidx,
                  const float* __restrict__ pseudo,
                  const float* __restrict__ weight,
                  const float* __restrict__ rootw,
                  const float* __restrict__ bias,
                  const int* __restrict__ offsets,
                  const int* __restrict__ cursor,   // post-scatter: row end offsets
                  const int* __restrict__ counts,   // row degrees
                  const int* __restrict__ sorted,
                  float* __restrict__ out)
{
    __shared__ float hs[ROWS_PB * HROW];            // 105600 B fp32 h tile
    __shared__ unsigned short wb[KTOT * 1024];      //  51200 B bf16 W, B-frag order
    __shared__ float rw[32 * 33];                   //   4224 B root weight
    __shared__ float bs[32];                        //    128 B bias

    const int tid = threadIdx.x;

    // ---- stage: W -> bf16 in MFMA B-fragment order [k][colhalf][lane][j] ----
    for (int idx = tid; idx < KTOT * 1024; idx += 1024) {
        int k = idx >> 10;
        int r = idx & 1023;
        int i = r >> 5;       // in-channel
        int o = r & 31;       // out-channel
        __hip_bfloat16 wv = __float2bfloat16(weight[idx]);
        int pos = (k << 10) | ((o >> 4) << 9) | ((((i >> 3) << 4) | (o & 15)) << 3) | (i & 7);
        wb[pos] = __builtin_bit_cast(unsigned short, wv);
    }
    {   // root weight (pitch 33) + bias
        int i = tid >> 5, o = tid & 31;
        rw[i * 33 + o] = rootw[tid];
        if (tid < 32) bs[tid] = bias[tid];
    }
    {   // zero h tile
        float4 z = {0.f, 0.f, 0.f, 0.f};
        for (int i4 = tid; i4 < (ROWS_PB * HROW) / 4; i4 += 1024)
            ((float4*)hs)[i4] = z;
    }
    __syncthreads();

    // ---- edge phase: scatter b_s * x_j into h via LDS atomics ----
    const int row0  = blockIdx.x * ROWS_PB;
    const int start = offsets[row0];
    const int end   = cursor[row0 + ROWS_PB - 1];   // offsets[last] + counts[last]

    const int t   = tid >> 3;          // team 0..127
    const int sub = tid & 7;           // 4 channels per lane

    for (int e0 = start + t; e0 < end; e0 += TEAMS) {
        int e   = sorted[e0];
        int row = eidx[e] - row0;
        int col = eidx[EE + e];

        // degree-1 spline basis, scale = K-1 = 4 (open)
        const float2 ps = *(const float2*)(pseudo + 2 * e);
        float p0 = ps.x * 4.0f, p1 = ps.y * 4.0f;
        float l0f = floorf(p0), l1f = floorf(p1);
        float f0 = p0 - l0f, f1 = p1 - l1f;
        int l0 = (int)l0f, l1 = (int)l1f;
        int i0a = min(max(l0, 0), 4),     i0b = min(max(l0 + 1, 0), 4);
        int i1a = min(max(l1, 0), 4),     i1b = min(max(l1 + 1, 0), 4);
        float b0 = (1.0f - f0) * (1.0f - f1); int k0 = i0a + 5 * i1a;
        float b1 = (1.0f - f0) * f1;          int k1 = i0a + 5 * i1b;
        float b2 = f0 * (1.0f - f1);          int k2 = i0b + 5 * i1a;
        float b3 = f0 * f1;                   int k3 = i0b + 5 * i1b;

        float4 xv = *(const float4*)(x + col * 32 + sub * 4);
        float xa[4] = {xv.x, xv.y, xv.z, xv.w};
        float* hp  = &hs[row * HROW + sub * 4];
        float* q0 = hp + k0 * HP;
        float* q1 = hp + k1 * HP;
        float* q2 = hp + k2 * HP;
        float* q3 = hp + k3 * HP;
        #pragma unroll
        for (int c = 0; c < 4; ++c) {
            atomicAdd(q0 + c, b0 * xa[c]);
            atomicAdd(q1 + c, b1 * xa[c]);
            atomicAdd(q2 + c, b2 * xa[c]);
            atomicAdd(q3 + c, b3 * xa[c]);
        }
    }
    __syncthreads();

    // ---- GEMM phase: out32x32 = h(32x800) x W(800x32), 4 waves, MFMA ----
    const int wid  = tid >> 6;
    const int lane = tid & 63;
    f32x4 acc = {0.f, 0.f, 0.f, 0.f};
    if (wid < 4) {
        const int rh   = wid >> 1;      // row half of output
        const int chh  = wid & 1;       // col half of output
        const int lrow = lane & 15;
        const int kg   = lane >> 4;     // k-subgroup of 8
        const float* hb = &hs[(rh * 16 + lrow) * HROW + kg * 8];
        const unsigned short* wp = &wb[(chh << 9) | (lane << 3)];
        for (int k = 0; k < KTOT; ++k) {
            const float* hpk = hb + k * HP;
            short8 a;
            #pragma unroll
            for (int j = 0; j < 8; ++j) {
                __hip_bfloat16 hv = __float2bfloat16(hpk[j]);
                a[j] = __builtin_bit_cast(short, hv);
            }
            short8 b = *(const short8*)(wp + (k << 10));
            acc = __builtin_amdgcn_mfma_f32_16x16x32_bf16(a, b, acc, 0, 0, 0);
        }
    }
    __syncthreads();   // all GEMM reads of hs done before otile overwrites it
    if (wid < 4) {
        const int rh  = wid >> 1;
        const int chh = wid & 1;
        int orow = rh * 16 + (lane >> 4) * 4;   // C/D layout: row=(l>>4)*4+reg
        int ocol = chh * 16 + (lane & 15);      //             col=l&15
        #pragma unroll
        for (int q = 0; q < 4; ++q)
            hs[(orow + q) * 33 + ocol] = acc[q];
    }
    __syncthreads();

    // ---- flush: /deg + x@root_weight + bias, coalesced store ----
    {
        int r = tid >> 5, ch = tid & 31;
        int row = row0 + r;
        float s  = hs[r * 33 + ch];
        float dg = fmaxf((float)counts[row], 1.0f);
        float v  = 0.0f;
        #pragma unroll
        for (int i = 0; i < 32; ++i)
            v = fmaf(x[row * 32 + i], rw[i * 33 + ch], v);
        out[row * 32 + ch] = s / dg + v + bs[ch];
    }
}

extern "C" void kernel_launch(void* const* d_in, const int* in_sizes, int n_in,
                              void* d_out, int out_size, void* d_ws, size_t ws_size,
                              hipStream_t stream) {
    const float* x      = (const float*)d_in[0];
    const int*   eidx   = (const int*)d_in[1];
    const float* pseudo = (const float*)d_in[2];
    const float* weight = (const float*)d_in[3];
    const float* rootw  = (const float*)d_in[4];
    const float* bias   = (const float*)d_in[5];
    float* out = (float*)d_out;

    int* ws      = (int*)d_ws;
    int* counts  = ws + WS_COUNTS;
    int* offsets = ws + WS_OFFSETS;
    int* cursor  = ws + WS_CURSOR;
    int* blksum  = ws + WS_BLKSUM;
    int* sorted  = ws + WS_SORTED;

    hipMemsetAsync(counts, 0, (size_t)NN * sizeof(int), stream);

    hist_kernel   <<<2048, 256, 0, stream>>>(eidx, counts);
    scan1_kernel  <<<SCAN_NBLK, 1024, 0, stream>>>(counts, offsets, blksum);
    scan2_kernel  <<<1, 128, 0, stream>>>(blksum);
    scan3_kernel  <<<SCAN_NBLK, 1024, 0, stream>>>(offsets, blksum, cursor);
    scatter_kernel<<<2048, 256, 0, stream>>>(eidx, cursor, sorted);

    block_kernel<<<NBLK, 1024, 0, stream>>>(
        x, eidx, pseudo, weight, rootw, bias, offsets, cursor, counts, sorted, out);
}

// Round 2
// 1369.018 us; speedup vs baseline: 1.0666x; 1.0666x over previous
//
#include <hip/hip_runtime.h>
#include <hip/hip_bf16.h>

// SplineConv (degree-1 B-spline, DIM=2, K=5, open), N=100000, E=1600000, 32->32.
// R9: R8 was latency-dead (VALUBusy 3.8%, MfmaUtil 0.17%, 1 block/CU from a
//     161KB LDS footprint; 100KB W re-staged per block = 320MB of the 390MB
//     total fetch; barrier-serialized phases with nothing to overlap).
//     R9 restructures:
//     - 16-row tiles, hs = 52.8KB -> 3 blocks/CU (24 waves), phases overlap
//       across blocks.
//     - W converted ONCE to bf16 B-fragment order in workspace (wconv kernel);
//       GEMM reads fragments from global (L2-resident broadcast). No per-block
//       W staging.
//     - scatter packs an 8B payload {f0,f1 u16 | col | k-bits | row&15} at the
//       sorted position: conv edge phase = 1 coalesced 8B load + 1 x[col] load
//       (chain depth 2 instead of 4), then 16 ds_add_f32 (k*33 pitch spreads
//       banks).
//     - /deg + x@root + bias fused into the MFMA epilogue (2 waves); no otile,
//       no flush phase, 2 barriers total.

#define NN   100000
#define EE   1600000
#define KTOT 25

#define ROWS_PB 16
#define NBLK    (NN / ROWS_PB)        // 6250 exact, no tail
#define HP      33                    // dword pitch per k-slot (k*33 mod 32 = k: bank rotation)
#define HROW    (KTOT * HP)           // 825 dwords per row
#define TEAMS   64                    // 512 threads / 8 lanes per team

// ws layout (int32 units): counts | offsets | cursor | blksum | wbf | pay
#define WS_COUNTS  0
#define WS_OFFSETS 100000
#define WS_CURSOR  200000
#define WS_BLKSUM  300000
#define WS_WBF     300128             // 25600 bf16 = 12800 ints
#define WS_PAY     312928             // 1.6M uint2 = 3.2M ints (byte off 16-aligned)
#define SCAN_NBLK  98                 // ceil(100000/1024)

typedef __attribute__((ext_vector_type(8))) short short8;
typedef __attribute__((ext_vector_type(4))) float f32x4;

__global__ void hist_kernel(const int* __restrict__ eidx, int* __restrict__ counts) {
    for (int e = blockIdx.x * blockDim.x + threadIdx.x; e < EE; e += gridDim.x * blockDim.x)
        atomicAdd(&counts[eidx[e]], 1);
}

__global__ __launch_bounds__(1024)
void scan1_kernel(const int* __restrict__ counts, int* __restrict__ offsets,
                  int* __restrict__ blksum) {
    __shared__ int buf[2][1024];
    int tid = threadIdx.x;
    int gid = blockIdx.x * 1024 + tid;
    int v = (gid < NN) ? counts[gid] : 0;
    buf[0][tid] = v;
    __syncthreads();
    int s = 0;
    for (int off = 1; off < 1024; off <<= 1) {
        int t = buf[s][tid];
        if (tid >= off) t += buf[s][tid - off];
        buf[1 - s][tid] = t;
        s ^= 1;
        __syncthreads();
    }
    if (gid < NN) offsets[gid] = buf[s][tid] - v;      // exclusive
    if (tid == 1023) blksum[blockIdx.x] = buf[s][tid]; // block total
}

__global__ __launch_bounds__(128)
void scan2_kernel(int* __restrict__ blksum) {
    __shared__ int buf[2][128];
    int tid = threadIdx.x;
    int v = (tid < SCAN_NBLK) ? blksum[tid] : 0;
    buf[0][tid] = v;
    __syncthreads();
    int s = 0;
    for (int off = 1; off < 128; off <<= 1) {
        int t = buf[s][tid];
        if (tid >= off) t += buf[s][tid - off];
        buf[1 - s][tid] = t;
        s ^= 1;
        __syncthreads();
    }
    if (tid < SCAN_NBLK) blksum[tid] = buf[s][tid] - v; // exclusive
}

__global__ __launch_bounds__(1024)
void scan3_kernel(int* __restrict__ offsets, const int* __restrict__ blksum,
                  int* __restrict__ cursor) {
    int gid = blockIdx.x * 1024 + threadIdx.x;
    if (gid < NN) {
        int o = offsets[gid] + blksum[blockIdx.x];
        offsets[gid] = o;
        cursor[gid] = o;
    }
}

// Convert weight fp32 -> bf16 in MFMA B-fragment order (one-shot, 25600 elems).
// pos bits: [k:5][colhalf:1][ (i>>3)<<4 | o&15 :5 ][ i&7 :3 ]  (same as verified R8)
__global__ __launch_bounds__(1024)
void wconv_kernel(const float* __restrict__ weight, unsigned short* __restrict__ wbf) {
    int idx = blockIdx.x * 1024 + threadIdx.x;   // grid 25
    int k = idx >> 10;
    int r = idx & 1023;
    int i = r >> 5;       // in-channel
    int o = r & 31;       // out-channel
    __hip_bfloat16 wv = __float2bfloat16(weight[idx]);
    int pos = (k << 10) | ((o >> 4) << 9) | ((((i >> 3) << 4) | (o & 15)) << 3) | (i & 7);
    wbf[pos] = __builtin_bit_cast(unsigned short, wv);
}

// Counting-sort scatter + payload pack: pay[pos] = {f0,f1 u16 | col,ibits,row&15}
__global__ void scatter_kernel(const int* __restrict__ eidx,
                               const float* __restrict__ pseudo,
                               int* __restrict__ cursor,
                               uint2* __restrict__ pay) {
    for (int e = blockIdx.x * blockDim.x + threadIdx.x; e < EE; e += gridDim.x * blockDim.x) {
        int row = eidx[e];
        int col = eidx[EE + e];
        const float2 ps = *(const float2*)(pseudo + 2 * e);
        float p0 = ps.x * 4.0f, p1 = ps.y * 4.0f;
        float l0f = floorf(p0), l1f = floorf(p1);
        float f0 = p0 - l0f, f1 = p1 - l1f;
        int l0 = (int)l0f, l1 = (int)l1f;
        int i0a = min(max(l0, 0), 4), i0b = min(max(l0 + 1, 0), 4);
        int i1a = min(max(l1, 0), 4), i1b = min(max(l1 + 1, 0), 4);
        unsigned u0 = (unsigned)(f0 * 65536.0f); if (u0 > 65535u) u0 = 65535u;
        unsigned u1 = (unsigned)(f1 * 65536.0f); if (u1 > 65535u) u1 = 65535u;
        unsigned ib = (unsigned)(i0a | (i1a << 3) | ((i0b - i0a) << 6) | ((i1b - i1a) << 7));
        unsigned w0 = u0 | (u1 << 16);
        unsigned w1 = (unsigned)col | (ib << 17) | ((unsigned)(row & 15) << 25);
        int pos = atomicAdd(&cursor[row], 1);
        pay[pos] = make_uint2(w0, w1);
    }
}

__global__ __launch_bounds__(512)
void conv_kernel(const float* __restrict__ x,
                 const uint2* __restrict__ pay,
                 const int* __restrict__ offsets,
                 const int* __restrict__ counts,
                 const unsigned short* __restrict__ wbf,
                 const float* __restrict__ rootw,
                 const float* __restrict__ bias,
                 float* __restrict__ out)
{
    __shared__ float hs[ROWS_PB * HROW];        // 52800 B -> 3 blocks/CU

    const int tid = threadIdx.x;
    {
        float4 z = {0.f, 0.f, 0.f, 0.f};
        for (int i4 = tid; i4 < (ROWS_PB * HROW) / 4; i4 += 512)
            ((float4*)hs)[i4] = z;
    }
    const int row0  = blockIdx.x * ROWS_PB;
    const int start = offsets[row0];
    const int end   = (blockIdx.x == NBLK - 1) ? EE : offsets[row0 + ROWS_PB];
    __syncthreads();

    // ---- edge phase: 1 payload load + 1 x load + 16 ds_add per lane ----
    const int t   = tid >> 3;          // team 0..63
    const int sub = tid & 7;           // 4 channels per lane

    for (int e0 = start + t; e0 < end; e0 += TEAMS) {
        uint2 pw = pay[e0];
        unsigned w0 = pw.x, w1 = pw.y;
        int col  = (int)(w1 & 0x1FFFFu);
        int ib   = (int)((w1 >> 17) & 0xFFu);
        int rloc = (int)((w1 >> 25) & 15u);
        float f0 = (float)(w0 & 0xFFFFu) * 1.52587890625e-05f;
        float f1 = (float)(w0 >> 16)     * 1.52587890625e-05f;
        int i0a = ib & 7, i1a = (ib >> 3) & 7;
        int i0b = i0a + ((ib >> 6) & 1), i1b = i1a + ((ib >> 7) & 1);
        float b0 = (1.0f - f0) * (1.0f - f1); int k0 = i0a + 5 * i1a;
        float b1 = (1.0f - f0) * f1;          int k1 = i0a + 5 * i1b;
        float b2 = f0 * (1.0f - f1);          int k2 = i0b + 5 * i1a;
        float b3 = f0 * f1;                   int k3 = i0b + 5 * i1b;

        float4 xv = *(const float4*)(x + col * 32 + sub * 4);
        float xa[4] = {xv.x, xv.y, xv.z, xv.w};
        float* hp = &hs[rloc * HROW + sub * 4];
        float* q0 = hp + k0 * HP;
        float* q1 = hp + k1 * HP;
        float* q2 = hp + k2 * HP;
        float* q3 = hp + k3 * HP;
        #pragma unroll
        for (int c = 0; c < 4; ++c) {
            atomicAdd(q0 + c, b0 * xa[c]);
            atomicAdd(q1 + c, b1 * xa[c]);
            atomicAdd(q2 + c, b2 * xa[c]);
            atomicAdd(q3 + c, b3 * xa[c]);
        }
    }
    __syncthreads();

    // ---- GEMM + fused epilogue: 2 waves, out16x32 = h(16x800) x W(800x32) ----
    const int wid  = tid >> 6;
    const int lane = tid & 63;
    if (wid < 2) {
        const int lrow = lane & 15;
        const int kg   = lane >> 4;
        const float* hb = &hs[lrow * HROW + kg * 8];
        const unsigned short* wp = wbf + (wid << 9) + (lane << 3);
        f32x4 acc = {0.f, 0.f, 0.f, 0.f};
        for (int k = 0; k < KTOT; ++k) {
            const float* hpk = hb + k * HP;
            short8 a;
            #pragma unroll
            for (int j = 0; j < 8; ++j) {
                __hip_bfloat16 hv = __float2bfloat16(hpk[j]);
                a[j] = __builtin_bit_cast(short, hv);
            }
            short8 b = *(const short8*)(wp + (k << 10));
            acc = __builtin_amdgcn_mfma_f32_16x16x32_bf16(a, b, acc, 0, 0, 0);
        }
        // epilogue: out = acc/deg + x@rootw + bias   (C/D: col=l&15, row=(l>>4)*4+q)
        const int ocol  = (wid << 4) | (lane & 15);
        const int rbase = row0 + ((lane >> 4) << 2);
        float rcol[32];
        #pragma unroll
        for (int i = 0; i < 32; ++i) rcol[i] = rootw[i * 32 + ocol];
        float bv = bias[ocol];
        #pragma unroll
        for (int q = 0; q < 4; ++q) {
            int row = rbase + q;
            float dg = fmaxf((float)counts[row], 1.0f);
            const float4* xr = (const float4*)(x + row * 32);
            float v = 0.f;
            #pragma unroll
            for (int m = 0; m < 8; ++m) {
                float4 xm = xr[m];
                v = fmaf(xm.x, rcol[4 * m + 0], v);
                v = fmaf(xm.y, rcol[4 * m + 1], v);
                v = fmaf(xm.z, rcol[4 * m + 2], v);
                v = fmaf(xm.w, rcol[4 * m + 3], v);
            }
            out[row * 32 + ocol] = acc[q] / dg + v + bv;
        }
    }
}

extern "C" void kernel_launch(void* const* d_in, const int* in_sizes, int n_in,
                              void* d_out, int out_size, void* d_ws, size_t ws_size,
                              hipStream_t stream) {
    const float* x      = (const float*)d_in[0];
    const int*   eidx   = (const int*)d_in[1];
    const float* pseudo = (const float*)d_in[2];
    const float* weight = (const float*)d_in[3];
    const float* rootw  = (const float*)d_in[4];
    const float* bias   = (const float*)d_in[5];
    float* out = (float*)d_out;

    int* ws      = (int*)d_ws;
    int* counts  = ws + WS_COUNTS;
    int* offsets = ws + WS_OFFSETS;
    int* cursor  = ws + WS_CURSOR;
    int* blksum  = ws + WS_BLKSUM;
    unsigned short* wbf = (unsigned short*)(ws + WS_WBF);
    uint2* pay   = (uint2*)(ws + WS_PAY);

    hipMemsetAsync(counts, 0, (size_t)NN * sizeof(int), stream);

    hist_kernel   <<<2048, 256, 0, stream>>>(eidx, counts);
    scan1_kernel  <<<SCAN_NBLK, 1024, 0, stream>>>(counts, offsets, blksum);
    scan2_kernel  <<<1, 128, 0, stream>>>(blksum);
    scan3_kernel  <<<SCAN_NBLK, 1024, 0, stream>>>(offsets, blksum, cursor);
    wconv_kernel  <<<25, 1024, 0, stream>>>(weight, wbf);
    scatter_kernel<<<2048, 256, 0, stream>>>(eidx, pseudo, cursor, pay);

    conv_kernel<<<NBLK, 512, 0, stream>>>(
        x, pay, offsets, counts, wbf, rootw, bias, out);
}

// Round 3
// 1347.949 us; speedup vs baseline: 1.0832x; 1.0156x over previous
//
#include <hip/hip_runtime.h>
#include <hip/hip_bf16.h>

// SplineConv (degree-1 B-spline, DIM=2, K=5, open), N=100000, E=1600000, 32->32.
// R10: ROOT CAUSE of R7-R9's latency-death found: HIP's atomicAdd(float*) on
//      LDS compiles to a CAS LOOP (ds_read+ds_cmpst+retry, ~120cy dependent
//      round-trip PER SCALAR ADD) without -munsafe-fp-atomics. 16 CAS chains
//      per edge = ~2-3K serialized cycles/edge -> matches the measured 2.67M
//      cycles/CU, the 2.7% VALUBusy, the low bank-conflict count, and R8~=R9
//      despite a 10x body-size difference. Fix: unsafeAtomicAdd -> native
//      ds_add_f32 (fire-and-forget). Plus batch-2 edge processing per team
//      (4 independent global loads in flight/wave covers pay->x gather
//      latency), __launch_bounds__(512,6) to keep 3 blocks/CU residency.

#define NN   100000
#define EE   1600000
#define KTOT 25

#define ROWS_PB 16
#define NBLK    (NN / ROWS_PB)        // 6250 exact, no tail
#define HP      33                    // dword pitch per k-slot
#define HROW    (KTOT * HP)           // 825 dwords per row
#define TEAMS   64                    // 512 threads / 8 lanes per team

// ws layout (int32 units): counts | offsets | cursor | blksum | wbf | pay
#define WS_COUNTS  0
#define WS_OFFSETS 100000
#define WS_CURSOR  200000
#define WS_BLKSUM  300000
#define WS_WBF     300128             // 25600 bf16 = 12800 ints
#define WS_PAY     312928             // 1.6M uint2 = 3.2M ints
#define SCAN_NBLK  98                 // ceil(100000/1024)

typedef __attribute__((ext_vector_type(8))) short short8;
typedef __attribute__((ext_vector_type(4))) float f32x4;

__global__ void hist_kernel(const int* __restrict__ eidx, int* __restrict__ counts) {
    for (int e = blockIdx.x * blockDim.x + threadIdx.x; e < EE; e += gridDim.x * blockDim.x)
        atomicAdd(&counts[eidx[e]], 1);
}

__global__ __launch_bounds__(1024)
void scan1_kernel(const int* __restrict__ counts, int* __restrict__ offsets,
                  int* __restrict__ blksum) {
    __shared__ int buf[2][1024];
    int tid = threadIdx.x;
    int gid = blockIdx.x * 1024 + tid;
    int v = (gid < NN) ? counts[gid] : 0;
    buf[0][tid] = v;
    __syncthreads();
    int s = 0;
    for (int off = 1; off < 1024; off <<= 1) {
        int t = buf[s][tid];
        if (tid >= off) t += buf[s][tid - off];
        buf[1 - s][tid] = t;
        s ^= 1;
        __syncthreads();
    }
    if (gid < NN) offsets[gid] = buf[s][tid] - v;      // exclusive
    if (tid == 1023) blksum[blockIdx.x] = buf[s][tid]; // block total
}

__global__ __launch_bounds__(128)
void scan2_kernel(int* __restrict__ blksum) {
    __shared__ int buf[2][128];
    int tid = threadIdx.x;
    int v = (tid < SCAN_NBLK) ? blksum[tid] : 0;
    buf[0][tid] = v;
    __syncthreads();
    int s = 0;
    for (int off = 1; off < 128; off <<= 1) {
        int t = buf[s][tid];
        if (tid >= off) t += buf[s][tid - off];
        buf[1 - s][tid] = t;
        s ^= 1;
        __syncthreads();
    }
    if (tid < SCAN_NBLK) blksum[tid] = buf[s][tid] - v; // exclusive
}

__global__ __launch_bounds__(1024)
void scan3_kernel(int* __restrict__ offsets, const int* __restrict__ blksum,
                  int* __restrict__ cursor) {
    int gid = blockIdx.x * 1024 + threadIdx.x;
    if (gid < NN) {
        int o = offsets[gid] + blksum[blockIdx.x];
        offsets[gid] = o;
        cursor[gid] = o;
    }
}

// Convert weight fp32 -> bf16 in MFMA B-fragment order (one-shot, 25600 elems).
__global__ __launch_bounds__(1024)
void wconv_kernel(const float* __restrict__ weight, unsigned short* __restrict__ wbf) {
    int idx = blockIdx.x * 1024 + threadIdx.x;   // grid 25
    int k = idx >> 10;
    int r = idx & 1023;
    int i = r >> 5;       // in-channel
    int o = r & 31;       // out-channel
    __hip_bfloat16 wv = __float2bfloat16(weight[idx]);
    int pos = (k << 10) | ((o >> 4) << 9) | ((((i >> 3) << 4) | (o & 15)) << 3) | (i & 7);
    wbf[pos] = __builtin_bit_cast(unsigned short, wv);
}

// Counting-sort scatter + payload pack: pay[pos] = {f0,f1 u16 | col,ibits,row&15}
__global__ void scatter_kernel(const int* __restrict__ eidx,
                               const float* __restrict__ pseudo,
                               int* __restrict__ cursor,
                               uint2* __restrict__ pay) {
    for (int e = blockIdx.x * blockDim.x + threadIdx.x; e < EE; e += gridDim.x * blockDim.x) {
        int row = eidx[e];
        int col = eidx[EE + e];
        const float2 ps = *(const float2*)(pseudo + 2 * e);
        float p0 = ps.x * 4.0f, p1 = ps.y * 4.0f;
        float l0f = floorf(p0), l1f = floorf(p1);
        float f0 = p0 - l0f, f1 = p1 - l1f;
        int l0 = (int)l0f, l1 = (int)l1f;
        int i0a = min(max(l0, 0), 4), i0b = min(max(l0 + 1, 0), 4);
        int i1a = min(max(l1, 0), 4), i1b = min(max(l1 + 1, 0), 4);
        unsigned u0 = (unsigned)(f0 * 65536.0f); if (u0 > 65535u) u0 = 65535u;
        unsigned u1 = (unsigned)(f1 * 65536.0f); if (u1 > 65535u) u1 = 65535u;
        unsigned ib = (unsigned)(i0a | (i1a << 3) | ((i0b - i0a) << 6) | ((i1b - i1a) << 7));
        unsigned w0 = u0 | (u1 << 16);
        unsigned w1 = (unsigned)col | (ib << 17) | ((unsigned)(row & 15) << 25);
        int pos = atomicAdd(&cursor[row], 1);
        pay[pos] = make_uint2(w0, w1);
    }
}

__global__ __launch_bounds__(512, 6)
void conv_kernel(const float* __restrict__ x,
                 const uint2* __restrict__ pay,
                 const int* __restrict__ offsets,
                 const int* __restrict__ counts,
                 const unsigned short* __restrict__ wbf,
                 const float* __restrict__ rootw,
                 const float* __restrict__ bias,
                 float* __restrict__ out)
{
    __shared__ float hs[ROWS_PB * HROW];        // 52800 B -> 3 blocks/CU

    const int tid = threadIdx.x;
    {
        float4 z = {0.f, 0.f, 0.f, 0.f};
        for (int i4 = tid; i4 < (ROWS_PB * HROW) / 4; i4 += 512)
            ((float4*)hs)[i4] = z;
    }
    const int row0  = blockIdx.x * ROWS_PB;
    const int start = offsets[row0];
    const int end   = (blockIdx.x == NBLK - 1) ? EE : offsets[row0 + ROWS_PB];
    __syncthreads();

    // ---- edge phase: batch-2 per team; native ds_add_f32 via unsafeAtomicAdd ----
    const int t    = tid >> 3;         // team 0..63
    const int sub4 = (tid & 7) * 4;    // 4 channels per lane

    for (int e0 = start + t; e0 < end; e0 += 2 * TEAMS) {
        int eB  = e0 + TEAMS;
        bool vB = eB < end;
        int eBc = vB ? eB : e0;

        uint2 pwA = pay[e0];
        uint2 pwB = pay[eBc];

        // decode A
        int colA  = (int)(pwA.y & 0x1FFFFu);
        int ibA   = (int)((pwA.y >> 17) & 0xFFu);
        int rlA   = (int)((pwA.y >> 25) & 15u);
        float fA0 = (float)(pwA.x & 0xFFFFu) * 1.52587890625e-05f;
        float fA1 = (float)(pwA.x >> 16)     * 1.52587890625e-05f;
        // decode B
        int colB  = (int)(pwB.y & 0x1FFFFu);
        int ibB   = (int)((pwB.y >> 17) & 0xFFu);
        int rlB   = (int)((pwB.y >> 25) & 15u);
        float fB0 = (float)(pwB.x & 0xFFFFu) * 1.52587890625e-05f;
        float fB1 = (float)(pwB.x >> 16)     * 1.52587890625e-05f;

        float4 xvA = *(const float4*)(x + colA * 32 + sub4);
        float4 xvB = *(const float4*)(x + colB * 32 + sub4);

        {   // edge A
            int i0a = ibA & 7, i1a = (ibA >> 3) & 7;
            int i0b = i0a + ((ibA >> 6) & 1), i1b = i1a + ((ibA >> 7) & 1);
            float b0 = (1.0f - fA0) * (1.0f - fA1); int k0 = i0a + 5 * i1a;
            float b1 = (1.0f - fA0) * fA1;          int k1 = i0a + 5 * i1b;
            float b2 = fA0 * (1.0f - fA1);          int k2 = i0b + 5 * i1a;
            float b3 = fA0 * fA1;                   int k3 = i0b + 5 * i1b;
            float xa[4] = {xvA.x, xvA.y, xvA.z, xvA.w};
            float* hp = &hs[rlA * HROW + sub4];
            float* q0 = hp + k0 * HP;
            float* q1 = hp + k1 * HP;
            float* q2 = hp + k2 * HP;
            float* q3 = hp + k3 * HP;
            #pragma unroll
            for (int c = 0; c < 4; ++c) {
                unsafeAtomicAdd(q0 + c, b0 * xa[c]);
                unsafeAtomicAdd(q1 + c, b1 * xa[c]);
                unsafeAtomicAdd(q2 + c, b2 * xa[c]);
                unsafeAtomicAdd(q3 + c, b3 * xa[c]);
            }
        }
        if (vB) {   // edge B
            int i0a = ibB & 7, i1a = (ibB >> 3) & 7;
            int i0b = i0a + ((ibB >> 6) & 1), i1b = i1a + ((ibB >> 7) & 1);
            float b0 = (1.0f - fB0) * (1.0f - fB1); int k0 = i0a + 5 * i1a;
            float b1 = (1.0f - fB0) * fB1;          int k1 = i0a + 5 * i1b;
            float b2 = fB0 * (1.0f - fB1);          int k2 = i0b + 5 * i1a;
            float b3 = fB0 * fB1;                   int k3 = i0b + 5 * i1b;
            float xa[4] = {xvB.x, xvB.y, xvB.z, xvB.w};
            float* hp = &hs[rlB * HROW + sub4];
            float* q0 = hp + k0 * HP;
            float* q1 = hp + k1 * HP;
            float* q2 = hp + k2 * HP;
            float* q3 = hp + k3 * HP;
            #pragma unroll
            for (int c = 0; c < 4; ++c) {
                unsafeAtomicAdd(q0 + c, b0 * xa[c]);
                unsafeAtomicAdd(q1 + c, b1 * xa[c]);
                unsafeAtomicAdd(q2 + c, b2 * xa[c]);
                unsafeAtomicAdd(q3 + c, b3 * xa[c]);
            }
        }
    }
    __syncthreads();

    // ---- GEMM + fused epilogue: 2 waves, out16x32 = h(16x800) x W(800x32) ----
    const int wid  = tid >> 6;
    const int lane = tid & 63;
    if (wid < 2) {
        const int lrow = lane & 15;
        const int kg   = lane >> 4;
        const float* hb = &hs[lrow * HROW + kg * 8];
        const unsigned short* wp = wbf + (wid << 9) + (lane << 3);
        f32x4 acc = {0.f, 0.f, 0.f, 0.f};
        for (int k = 0; k < KTOT; ++k) {
            const float* hpk = hb + k * HP;
            short8 a;
            #pragma unroll
            for (int j = 0; j < 8; ++j) {
                __hip_bfloat16 hv = __float2bfloat16(hpk[j]);
                a[j] = __builtin_bit_cast(short, hv);
            }
            short8 b = *(const short8*)(wp + (k << 10));
            acc = __builtin_amdgcn_mfma_f32_16x16x32_bf16(a, b, acc, 0, 0, 0);
        }
        // epilogue: out = acc/deg + x@rootw + bias   (C/D: col=l&15, row=(l>>4)*4+q)
        const int ocol  = (wid << 4) | (lane & 15);
        const int rbase = row0 + ((lane >> 4) << 2);
        float rcol[32];
        #pragma unroll
        for (int i = 0; i < 32; ++i) rcol[i] = rootw[i * 32 + ocol];
        float bv = bias[ocol];
        #pragma unroll
        for (int q = 0; q < 4; ++q) {
            int row = rbase + q;
            float dg = fmaxf((float)counts[row], 1.0f);
            const float4* xr = (const float4*)(x + row * 32);
            float v = 0.f;
            #pragma unroll
            for (int m = 0; m < 8; ++m) {
                float4 xm = xr[m];
                v = fmaf(xm.x, rcol[4 * m + 0], v);
                v = fmaf(xm.y, rcol[4 * m + 1], v);
                v = fmaf(xm.z, rcol[4 * m + 2], v);
                v = fmaf(xm.w, rcol[4 * m + 3], v);
            }
            out[row * 32 + ocol] = acc[q] / dg + v + bv;
        }
    }
}

extern "C" void kernel_launch(void* const* d_in, const int* in_sizes, int n_in,
                              void* d_out, int out_size, void* d_ws, size_t ws_size,
                              hipStream_t stream) {
    const float* x      = (const float*)d_in[0];
    const int*   eidx   = (const int*)d_in[1];
    const float* pseudo = (const float*)d_in[2];
    const float* weight = (const float*)d_in[3];
    const float* rootw  = (const float*)d_in[4];
    const float* bias   = (const float*)d_in[5];
    float* out = (float*)d_out;

    int* ws      = (int*)d_ws;
    int* counts  = ws + WS_COUNTS;
    int* offsets = ws + WS_OFFSETS;
    int* cursor  = ws + WS_CURSOR;
    int* blksum  = ws + WS_BLKSUM;
    unsigned short* wbf = (unsigned short*)(ws + WS_WBF);
    uint2* pay   = (uint2*)(ws + WS_PAY);

    hipMemsetAsync(counts, 0, (size_t)NN * sizeof(int), stream);

    hist_kernel   <<<2048, 256, 0, stream>>>(eidx, counts);
    scan1_kernel  <<<SCAN_NBLK, 1024, 0, stream>>>(counts, offsets, blksum);
    scan2_kernel  <<<1, 128, 0, stream>>>(blksum);
    scan3_kernel  <<<SCAN_NBLK, 1024, 0, stream>>>(offsets, blksum, cursor);
    wconv_kernel  <<<25, 1024, 0, stream>>>(weight, wbf);
    scatter_kernel<<<2048, 256, 0, stream>>>(eidx, pseudo, cursor, pay);

    conv_kernel<<<NBLK, 512, 0, stream>>>(
        x, pay, offsets, counts, wbf, rootw, bias, out);
}

// Round 4
// 1345.933 us; speedup vs baseline: 1.0848x; 1.0015x over previous
//
#include <hip/hip_runtime.h>
#include <hip/hip_bf16.h>

// SplineConv (degree-1 B-spline, DIM=2, K=5, open), N=100000, E=1600000, 32->32.
// R11: R10 proved the bottleneck is the LDS fp32 atomic path itself (unsafe
//      AtomicAdd changed nothing; everything else idle). Two candidate
//      mechanisms -- CAS-loop lowering, or same-address ds_add serialization
//      from ~8 teams sharing one row -- share the same structural root:
//      concurrent teams hammering one row's h slots. R11 removes it:
//      - ONE TEAM PER ROW (16 lanes, lane owns 2 channels): every (row,k,c)
//        LDS address is written by exactly one lane. Zero contention by
//        construction.
//      - ds_add_f32 via inline asm (fire-and-forget, provably not CAS).
//        LDS aperture is 4GiB-aligned -> low 32 bits of a __shared__ pointer
//        are the DS offset. Explicit s_waitcnt lgkmcnt(0) before the barrier
//        (inline-asm DS ops aren't compiler-tracked).
//      - edge loop unrolled x2, payload loads issued up front.
//      - 256 threads; hs 52.8KB -> 3 blocks/CU; GEMM + fused epilogue
//        verbatim from verified R9.

#define NN   100000
#define EE   1600000
#define KTOT 25

#define ROWS_PB 16
#define NBLK    (NN / ROWS_PB)        // 6250 exact, no tail
#define HP      33                    // dword pitch per k-slot (132 bytes)
#define HROW    (KTOT * HP)           // 825 dwords per row

// ws layout (int32 units): counts | offsets | cursor | blksum | wbf | pay
#define WS_COUNTS  0
#define WS_OFFSETS 100000
#define WS_CURSOR  200000
#define WS_BLKSUM  300000
#define WS_WBF     300128             // 25600 bf16 = 12800 ints
#define WS_PAY     312928             // 1.6M uint2 = 3.2M ints
#define SCAN_NBLK  98                 // ceil(100000/1024)

typedef __attribute__((ext_vector_type(8))) short short8;
typedef __attribute__((ext_vector_type(4))) float f32x4;

__device__ __forceinline__ void lds_add2(unsigned off, float a, float b) {
    // two native LDS fp32 atomic adds: channel c and c+1 (offset:4)
    asm volatile("ds_add_f32 %0, %1\n\tds_add_f32 %0, %2 offset:4"
                 :: "v"(off), "v"(a), "v"(b));
}

__global__ void hist_kernel(const int* __restrict__ eidx, int* __restrict__ counts) {
    for (int e = blockIdx.x * blockDim.x + threadIdx.x; e < EE; e += gridDim.x * blockDim.x)
        atomicAdd(&counts[eidx[e]], 1);
}

__global__ __launch_bounds__(1024)
void scan1_kernel(const int* __restrict__ counts, int* __restrict__ offsets,
                  int* __restrict__ blksum) {
    __shared__ int buf[2][1024];
    int tid = threadIdx.x;
    int gid = blockIdx.x * 1024 + tid;
    int v = (gid < NN) ? counts[gid] : 0;
    buf[0][tid] = v;
    __syncthreads();
    int s = 0;
    for (int off = 1; off < 1024; off <<= 1) {
        int t = buf[s][tid];
        if (tid >= off) t += buf[s][tid - off];
        buf[1 - s][tid] = t;
        s ^= 1;
        __syncthreads();
    }
    if (gid < NN) offsets[gid] = buf[s][tid] - v;      // exclusive
    if (tid == 1023) blksum[blockIdx.x] = buf[s][tid]; // block total
}

__global__ __launch_bounds__(128)
void scan2_kernel(int* __restrict__ blksum) {
    __shared__ int buf[2][128];
    int tid = threadIdx.x;
    int v = (tid < SCAN_NBLK) ? blksum[tid] : 0;
    buf[0][tid] = v;
    __syncthreads();
    int s = 0;
    for (int off = 1; off < 128; off <<= 1) {
        int t = buf[s][tid];
        if (tid >= off) t += buf[s][tid - off];
        buf[1 - s][tid] = t;
        s ^= 1;
        __syncthreads();
    }
    if (tid < SCAN_NBLK) blksum[tid] = buf[s][tid] - v; // exclusive
}

__global__ __launch_bounds__(1024)
void scan3_kernel(int* __restrict__ offsets, const int* __restrict__ blksum,
                  int* __restrict__ cursor) {
    int gid = blockIdx.x * 1024 + threadIdx.x;
    if (gid < NN) {
        int o = offsets[gid] + blksum[blockIdx.x];
        offsets[gid] = o;
        cursor[gid] = o;
    }
}

// Convert weight fp32 -> bf16 in MFMA B-fragment order (one-shot, 25600 elems).
__global__ __launch_bounds__(1024)
void wconv_kernel(const float* __restrict__ weight, unsigned short* __restrict__ wbf) {
    int idx = blockIdx.x * 1024 + threadIdx.x;   // grid 25
    int k = idx >> 10;
    int r = idx & 1023;
    int i = r >> 5;       // in-channel
    int o = r & 31;       // out-channel
    __hip_bfloat16 wv = __float2bfloat16(weight[idx]);
    int pos = (k << 10) | ((o >> 4) << 9) | ((((i >> 3) << 4) | (o & 15)) << 3) | (i & 7);
    wbf[pos] = __builtin_bit_cast(unsigned short, wv);
}

// Counting-sort scatter + payload pack: pay[pos] = {f0,f1 u16 | col,ibits}
__global__ void scatter_kernel(const int* __restrict__ eidx,
                               const float* __restrict__ pseudo,
                               int* __restrict__ cursor,
                               uint2* __restrict__ pay) {
    for (int e = blockIdx.x * blockDim.x + threadIdx.x; e < EE; e += gridDim.x * blockDim.x) {
        int row = eidx[e];
        int col = eidx[EE + e];
        const float2 ps = *(const float2*)(pseudo + 2 * e);
        float p0 = ps.x * 4.0f, p1 = ps.y * 4.0f;
        float l0f = floorf(p0), l1f = floorf(p1);
        float f0 = p0 - l0f, f1 = p1 - l1f;
        int l0 = (int)l0f, l1 = (int)l1f;
        int i0a = min(max(l0, 0), 4), i0b = min(max(l0 + 1, 0), 4);
        int i1a = min(max(l1, 0), 4), i1b = min(max(l1 + 1, 0), 4);
        unsigned u0 = (unsigned)(f0 * 65536.0f); if (u0 > 65535u) u0 = 65535u;
        unsigned u1 = (unsigned)(f1 * 65536.0f); if (u1 > 65535u) u1 = 65535u;
        unsigned ib = (unsigned)(i0a | (i1a << 3) | ((i0b - i0a) << 6) | ((i1b - i1a) << 7));
        unsigned w0 = u0 | (u1 << 16);
        unsigned w1 = (unsigned)col | (ib << 17);
        int pos = atomicAdd(&cursor[row], 1);
        pay[pos] = make_uint2(w0, w1);
    }
}

__device__ __forceinline__ void do_edge(unsigned base, uint2 pw, float2 xv) {
    int ib = (int)((pw.y >> 17) & 0xFFu);
    float f0 = (float)(pw.x & 0xFFFFu) * 1.52587890625e-05f;
    float f1 = (float)(pw.x >> 16)     * 1.52587890625e-05f;
    int i0a = ib & 7, i1a = (ib >> 3) & 7;
    int i0b = i0a + ((ib >> 6) & 1), i1b = i1a + ((ib >> 7) & 1);
    float g0 = 1.0f - f0, g1 = 1.0f - f1;
    unsigned oa = base + (unsigned)i0a * 132u;   // byte offsets: k = i0 + 5*i1
    unsigned ob = base + (unsigned)i0b * 132u;   //   -> i0*132 + i1*660
    unsigned a00 = oa + (unsigned)i1a * 660u;
    unsigned a01 = oa + (unsigned)i1b * 660u;
    unsigned a10 = ob + (unsigned)i1a * 660u;
    unsigned a11 = ob + (unsigned)i1b * 660u;
    float b0 = g0 * g1, b1 = g0 * f1, b2 = f0 * g1, b3 = f0 * f1;
    lds_add2(a00, b0 * xv.x, b0 * xv.y);
    lds_add2(a01, b1 * xv.x, b1 * xv.y);
    lds_add2(a10, b2 * xv.x, b2 * xv.y);
    lds_add2(a11, b3 * xv.x, b3 * xv.y);
}

__global__ __launch_bounds__(256, 3)
void conv_kernel(const float* __restrict__ x,
                 const uint2* __restrict__ pay,
                 const int* __restrict__ offsets,
                 const int* __restrict__ counts,
                 const unsigned short* __restrict__ wbf,
                 const float* __restrict__ rootw,
                 const float* __restrict__ bias,
                 float* __restrict__ out)
{
    __shared__ float hs[ROWS_PB * HROW];        // 52800 B -> 3 blocks/CU

    const int tid = threadIdx.x;
    {
        float4 z = {0.f, 0.f, 0.f, 0.f};
        for (int i4 = tid; i4 < (ROWS_PB * HROW) / 4; i4 += 256)
            ((float4*)hs)[i4] = z;
    }
    __syncthreads();

    const int row0 = blockIdx.x * ROWS_PB;

    // ---- edge phase: one 16-lane team per row; lane owns channels c2,c2+1 ----
    {
        const int team = tid >> 4;             // 0..15 -> row
        const int l    = tid & 15;
        const int c2   = l * 2;
        const int row  = row0 + team;
        const int s    = offsets[row];
        const int e    = s + counts[row];

        unsigned base = (unsigned)(unsigned long long)(&hs[team * HROW + c2]);

        int e0 = s;
        for (; e0 + 1 < e; e0 += 2) {
            uint2 pA = pay[e0];
            uint2 pB = pay[e0 + 1];
            int colA = (int)(pA.y & 0x1FFFFu);
            int colB = (int)(pB.y & 0x1FFFFu);
            float2 xA = *(const float2*)(x + colA * 32 + c2);
            float2 xB = *(const float2*)(x + colB * 32 + c2);
            do_edge(base, pA, xA);
            do_edge(base, pB, xB);
        }
        if (e0 < e) {
            uint2 pA = pay[e0];
            int colA = (int)(pA.y & 0x1FFFFu);
            float2 xA = *(const float2*)(x + colA * 32 + c2);
            do_edge(base, pA, xA);
        }
    }
    asm volatile("s_waitcnt lgkmcnt(0)");   // drain inline-asm ds_add ops
    __syncthreads();

    // ---- GEMM + fused epilogue: 2 waves, out16x32 = h(16x800) x W(800x32) ----
    const int wid  = tid >> 6;
    const int lane = tid & 63;
    if (wid < 2) {
        const int lrow = lane & 15;
        const int kg   = lane >> 4;
        const float* hb = &hs[lrow * HROW + kg * 8];
        const unsigned short* wp = wbf + (wid << 9) + (lane << 3);
        f32x4 acc = {0.f, 0.f, 0.f, 0.f};
        for (int k = 0; k < KTOT; ++k) {
            const float* hpk = hb + k * HP;
            short8 a;
            #pragma unroll
            for (int j = 0; j < 8; ++j) {
                __hip_bfloat16 hv = __float2bfloat16(hpk[j]);
                a[j] = __builtin_bit_cast(short, hv);
            }
            short8 b = *(const short8*)(wp + (k << 10));
            acc = __builtin_amdgcn_mfma_f32_16x16x32_bf16(a, b, acc, 0, 0, 0);
        }
        // epilogue: out = acc/deg + x@rootw + bias   (C/D: col=l&15, row=(l>>4)*4+q)
        const int ocol  = (wid << 4) | (lane & 15);
        const int rbase = row0 + ((lane >> 4) << 2);
        float rcol[32];
        #pragma unroll
        for (int i = 0; i < 32; ++i) rcol[i] = rootw[i * 32 + ocol];
        float bv = bias[ocol];
        #pragma unroll
        for (int q = 0; q < 4; ++q) {
            int row = rbase + q;
            float dg = fmaxf((float)counts[row], 1.0f);
            const float4* xr = (const float4*)(x + row * 32);
            float v = 0.f;
            #pragma unroll
            for (int m = 0; m < 8; ++m) {
                float4 xm = xr[m];
                v = fmaf(xm.x, rcol[4 * m + 0], v);
                v = fmaf(xm.y, rcol[4 * m + 1], v);
                v = fmaf(xm.z, rcol[4 * m + 2], v);
                v = fmaf(xm.w, rcol[4 * m + 3], v);
            }
            out[row * 32 + ocol] = acc[q] / dg + v + bv;
        }
    }
}

extern "C" void kernel_launch(void* const* d_in, const int* in_sizes, int n_in,
                              void* d_out, int out_size, void* d_ws, size_t ws_size,
                              hipStream_t stream) {
    const float* x      = (const float*)d_in[0];
    const int*   eidx   = (const int*)d_in[1];
    const float* pseudo = (const float*)d_in[2];
    const float* weight = (const float*)d_in[3];
    const float* rootw  = (const float*)d_in[4];
    const float* bias   = (const float*)d_in[5];
    float* out = (float*)d_out;

    int* ws      = (int*)d_ws;
    int* counts  = ws + WS_COUNTS;
    int* offsets = ws + WS_OFFSETS;
    int* cursor  = ws + WS_CURSOR;
    int* blksum  = ws + WS_BLKSUM;
    unsigned short* wbf = (unsigned short*)(ws + WS_WBF);
    uint2* pay   = (uint2*)(ws + WS_PAY);

    hipMemsetAsync(counts, 0, (size_t)NN * sizeof(int), stream);

    hist_kernel   <<<2048, 256, 0, stream>>>(eidx, counts);
    scan1_kernel  <<<SCAN_NBLK, 1024, 0, stream>>>(counts, offsets, blksum);
    scan2_kernel  <<<1, 128, 0, stream>>>(blksum);
    scan3_kernel  <<<SCAN_NBLK, 1024, 0, stream>>>(offsets, blksum, cursor);
    wconv_kernel  <<<25, 1024, 0, stream>>>(weight, wbf);
    scatter_kernel<<<2048, 256, 0, stream>>>(eidx, pseudo, cursor, pay);

    conv_kernel<<<NBLK, 256, 0, stream>>>(
        x, pay, offsets, counts, wbf, rootw, bias, out);
}

// Round 5
// 408.192 us; speedup vs baseline: 3.5771x; 3.2973x over previous
//
#include <hip/hip_runtime.h>
#include <hip/hip_bf16.h>

// SplineConv (degree-1 B-spline, DIM=2, K=5, open), N=100000, E=1600000, 32->32.
// R12: R8-R11 all measured 1100+-12us despite 4 structurally different edge
//      phases. The only invariant: 128 scalar LDS fp32 ATOMIC adds per edge
//      (204.8M total). Fit: 800K adds/CU at 2.64M cy/CU = ~3.3 cy per scalar
//      LDS atomic -- the LDS atomic unit retires atomics near-serially per CU
//      (not bank-parallel), so ds_add_f32 throughput, not contention and not
//      CAS, is the wall (R11's zero-contention native-asm null proves it).
//      FIX: R11's ownership structure (one 16-lane team per row, lane owns
//      channels c2,c2+1) makes every (row,k,c) address single-writer for the
//      whole phase -> plain ds_read/v_add/ds_write RMW is race-free and runs
//      bank-parallel (~20x the atomic-unit throughput). No inline asm left,
//      so the compiler can also software-pipeline the pay->x load chain.

#define NN   100000
#define EE   1600000
#define KTOT 25

#define ROWS_PB 16
#define NBLK    (NN / ROWS_PB)        // 6250 exact, no tail
#define HP      33                    // dword pitch per k-slot (132 bytes)
#define HROW    (KTOT * HP)           // 825 dwords per row

// ws layout (int32 units): counts | offsets | cursor | blksum | wbf | pay
#define WS_COUNTS  0
#define WS_OFFSETS 100000
#define WS_CURSOR  200000
#define WS_BLKSUM  300000
#define WS_WBF     300128             // 25600 bf16 = 12800 ints
#define WS_PAY     312928             // 1.6M uint2 = 3.2M ints
#define SCAN_NBLK  98                 // ceil(100000/1024)

typedef __attribute__((ext_vector_type(8))) short short8;
typedef __attribute__((ext_vector_type(4))) float f32x4;

__global__ void hist_kernel(const int* __restrict__ eidx, int* __restrict__ counts) {
    for (int e = blockIdx.x * blockDim.x + threadIdx.x; e < EE; e += gridDim.x * blockDim.x)
        atomicAdd(&counts[eidx[e]], 1);
}

__global__ __launch_bounds__(1024)
void scan1_kernel(const int* __restrict__ counts, int* __restrict__ offsets,
                  int* __restrict__ blksum) {
    __shared__ int buf[2][1024];
    int tid = threadIdx.x;
    int gid = blockIdx.x * 1024 + tid;
    int v = (gid < NN) ? counts[gid] : 0;
    buf[0][tid] = v;
    __syncthreads();
    int s = 0;
    for (int off = 1; off < 1024; off <<= 1) {
        int t = buf[s][tid];
        if (tid >= off) t += buf[s][tid - off];
        buf[1 - s][tid] = t;
        s ^= 1;
        __syncthreads();
    }
    if (gid < NN) offsets[gid] = buf[s][tid] - v;      // exclusive
    if (tid == 1023) blksum[blockIdx.x] = buf[s][tid]; // block total
}

__global__ __launch_bounds__(128)
void scan2_kernel(int* __restrict__ blksum) {
    __shared__ int buf[2][128];
    int tid = threadIdx.x;
    int v = (tid < SCAN_NBLK) ? blksum[tid] : 0;
    buf[0][tid] = v;
    __syncthreads();
    int s = 0;
    for (int off = 1; off < 128; off <<= 1) {
        int t = buf[s][tid];
        if (tid >= off) t += buf[s][tid - off];
        buf[1 - s][tid] = t;
        s ^= 1;
        __syncthreads();
    }
    if (tid < SCAN_NBLK) blksum[tid] = buf[s][tid] - v; // exclusive
}

__global__ __launch_bounds__(1024)
void scan3_kernel(int* __restrict__ offsets, const int* __restrict__ blksum,
                  int* __restrict__ cursor) {
    int gid = blockIdx.x * 1024 + threadIdx.x;
    if (gid < NN) {
        int o = offsets[gid] + blksum[blockIdx.x];
        offsets[gid] = o;
        cursor[gid] = o;
    }
}

// Convert weight fp32 -> bf16 in MFMA B-fragment order (one-shot, 25600 elems).
__global__ __launch_bounds__(1024)
void wconv_kernel(const float* __restrict__ weight, unsigned short* __restrict__ wbf) {
    int idx = blockIdx.x * 1024 + threadIdx.x;   // grid 25
    int k = idx >> 10;
    int r = idx & 1023;
    int i = r >> 5;       // in-channel
    int o = r & 31;       // out-channel
    __hip_bfloat16 wv = __float2bfloat16(weight[idx]);
    int pos = (k << 10) | ((o >> 4) << 9) | ((((i >> 3) << 4) | (o & 15)) << 3) | (i & 7);
    wbf[pos] = __builtin_bit_cast(unsigned short, wv);
}

// Counting-sort scatter + payload pack: pay[pos] = {f0,f1 u16 | col,ibits}
__global__ void scatter_kernel(const int* __restrict__ eidx,
                               const float* __restrict__ pseudo,
                               int* __restrict__ cursor,
                               uint2* __restrict__ pay) {
    for (int e = blockIdx.x * blockDim.x + threadIdx.x; e < EE; e += gridDim.x * blockDim.x) {
        int row = eidx[e];
        int col = eidx[EE + e];
        const float2 ps = *(const float2*)(pseudo + 2 * e);
        float p0 = ps.x * 4.0f, p1 = ps.y * 4.0f;
        float l0f = floorf(p0), l1f = floorf(p1);
        float f0 = p0 - l0f, f1 = p1 - l1f;
        int l0 = (int)l0f, l1 = (int)l1f;
        int i0a = min(max(l0, 0), 4), i0b = min(max(l0 + 1, 0), 4);
        int i1a = min(max(l1, 0), 4), i1b = min(max(l1 + 1, 0), 4);
        unsigned u0 = (unsigned)(f0 * 65536.0f); if (u0 > 65535u) u0 = 65535u;
        unsigned u1 = (unsigned)(f1 * 65536.0f); if (u1 > 65535u) u1 = 65535u;
        unsigned ib = (unsigned)(i0a | (i1a << 3) | ((i0b - i0a) << 6) | ((i1b - i1a) << 7));
        unsigned w0 = u0 | (u1 << 16);
        unsigned w1 = (unsigned)col | (ib << 17);
        int pos = atomicAdd(&cursor[row], 1);
        pay[pos] = make_uint2(w0, w1);
    }
}

// Plain (non-atomic) LDS read-modify-write: race-free because this lane is the
// sole writer of (row, c2..c2+1) for the whole edge phase.
__device__ __forceinline__ void do_edge_rmw(float* hp, uint2 pw, float2 xv) {
    int ib = (int)((pw.y >> 17) & 0xFFu);
    float f0 = (float)(pw.x & 0xFFFFu) * 1.52587890625e-05f;
    float f1 = (float)(pw.x >> 16)     * 1.52587890625e-05f;
    int i0a = ib & 7, i1a = (ib >> 3) & 7;
    int i0b = i0a + ((ib >> 6) & 1), i1b = i1a + ((ib >> 7) & 1);
    float g0 = 1.0f - f0, g1 = 1.0f - f1;
    // k = i0 + 5*i1  ->  dword offset k*33 = i0*33 + i1*165
    float* qa  = hp + i0a * 33;
    float* qb  = hp + i0b * 33;
    float* q00 = qa + i1a * 165;
    float* q01 = qa + i1b * 165;
    float* q10 = qb + i1a * 165;
    float* q11 = qb + i1b * 165;
    float b0 = g0 * g1, b1 = g0 * f1, b2 = f0 * g1, b3 = f0 * f1;
    q00[0] += b0 * xv.x;  q00[1] += b0 * xv.y;
    q01[0] += b1 * xv.x;  q01[1] += b1 * xv.y;
    q10[0] += b2 * xv.x;  q10[1] += b2 * xv.y;
    q11[0] += b3 * xv.x;  q11[1] += b3 * xv.y;
}

__global__ __launch_bounds__(256, 3)
void conv_kernel(const float* __restrict__ x,
                 const uint2* __restrict__ pay,
                 const int* __restrict__ offsets,
                 const int* __restrict__ counts,
                 const unsigned short* __restrict__ wbf,
                 const float* __restrict__ rootw,
                 const float* __restrict__ bias,
                 float* __restrict__ out)
{
    __shared__ float hs[ROWS_PB * HROW];        // 52800 B -> 3 blocks/CU

    const int tid = threadIdx.x;
    {
        float4 z = {0.f, 0.f, 0.f, 0.f};
        for (int i4 = tid; i4 < (ROWS_PB * HROW) / 4; i4 += 256)
            ((float4*)hs)[i4] = z;
    }
    __syncthreads();

    const int row0 = blockIdx.x * ROWS_PB;

    // ---- edge phase: one 16-lane team per row; lane owns channels c2,c2+1 ----
    {
        const int team = tid >> 4;             // 0..15 -> row
        const int l    = tid & 15;
        const int c2   = l * 2;
        const int row  = row0 + team;
        const int s    = offsets[row];
        const int e    = s + counts[row];

        float* hp = &hs[team * HROW + c2];

        int e0 = s;
        for (; e0 + 1 < e; e0 += 2) {
            uint2 pA = pay[e0];
            uint2 pB = pay[e0 + 1];
            int colA = (int)(pA.y & 0x1FFFFu);
            int colB = (int)(pB.y & 0x1FFFFu);
            float2 xA = *(const float2*)(x + colA * 32 + c2);
            float2 xB = *(const float2*)(x + colB * 32 + c2);
            do_edge_rmw(hp, pA, xA);
            do_edge_rmw(hp, pB, xB);
        }
        if (e0 < e) {
            uint2 pA = pay[e0];
            int colA = (int)(pA.y & 0x1FFFFu);
            float2 xA = *(const float2*)(x + colA * 32 + c2);
            do_edge_rmw(hp, pA, xA);
        }
    }
    __syncthreads();

    // ---- GEMM + fused epilogue: 2 waves, out16x32 = h(16x800) x W(800x32) ----
    const int wid  = tid >> 6;
    const int lane = tid & 63;
    if (wid < 2) {
        const int lrow = lane & 15;
        const int kg   = lane >> 4;
        const float* hb = &hs[lrow * HROW + kg * 8];
        const unsigned short* wp = wbf + (wid << 9) + (lane << 3);
        f32x4 acc = {0.f, 0.f, 0.f, 0.f};
        for (int k = 0; k < KTOT; ++k) {
            const float* hpk = hb + k * HP;
            short8 a;
            #pragma unroll
            for (int j = 0; j < 8; ++j) {
                __hip_bfloat16 hv = __float2bfloat16(hpk[j]);
                a[j] = __builtin_bit_cast(short, hv);
            }
            short8 b = *(const short8*)(wp + (k << 10));
            acc = __builtin_amdgcn_mfma_f32_16x16x32_bf16(a, b, acc, 0, 0, 0);
        }
        // epilogue: out = acc/deg + x@rootw + bias   (C/D: col=l&15, row=(l>>4)*4+q)
        const int ocol  = (wid << 4) | (lane & 15);
        const int rbase = row0 + ((lane >> 4) << 2);
        float rcol[32];
        #pragma unroll
        for (int i = 0; i < 32; ++i) rcol[i] = rootw[i * 32 + ocol];
        float bv = bias[ocol];
        #pragma unroll
        for (int q = 0; q < 4; ++q) {
            int row = rbase + q;
            float dg = fmaxf((float)counts[row], 1.0f);
            const float4* xr = (const float4*)(x + row * 32);
            float v = 0.f;
            #pragma unroll
            for (int m = 0; m < 8; ++m) {
                float4 xm = xr[m];
                v = fmaf(xm.x, rcol[4 * m + 0], v);
                v = fmaf(xm.y, rcol[4 * m + 1], v);
                v = fmaf(xm.z, rcol[4 * m + 2], v);
                v = fmaf(xm.w, rcol[4 * m + 3], v);
            }
            out[row * 32 + ocol] = acc[q] / dg + v + bv;
        }
    }
}

extern "C" void kernel_launch(void* const* d_in, const int* in_sizes, int n_in,
                              void* d_out, int out_size, void* d_ws, size_t ws_size,
                              hipStream_t stream) {
    const float* x      = (const float*)d_in[0];
    const int*   eidx   = (const int*)d_in[1];
    const float* pseudo = (const float*)d_in[2];
    const float* weight = (const float*)d_in[3];
    const float* rootw  = (const float*)d_in[4];
    const float* bias   = (const float*)d_in[5];
    float* out = (float*)d_out;

    int* ws      = (int*)d_ws;
    int* counts  = ws + WS_COUNTS;
    int* offsets = ws + WS_OFFSETS;
    int* cursor  = ws + WS_CURSOR;
    int* blksum  = ws + WS_BLKSUM;
    unsigned short* wbf = (unsigned short*)(ws + WS_WBF);
    uint2* pay   = (uint2*)(ws + WS_PAY);

    hipMemsetAsync(counts, 0, (size_t)NN * sizeof(int), stream);

    hist_kernel   <<<2048, 256, 0, stream>>>(eidx, counts);
    scan1_kernel  <<<SCAN_NBLK, 1024, 0, stream>>>(counts, offsets, blksum);
    scan2_kernel  <<<1, 128, 0, stream>>>(blksum);
    scan3_kernel  <<<SCAN_NBLK, 1024, 0, stream>>>(offsets, blksum, cursor);
    wconv_kernel  <<<25, 1024, 0, stream>>>(weight, wbf);
    scatter_kernel<<<2048, 256, 0, stream>>>(eidx, pseudo, cursor, pay);

    conv_kernel<<<NBLK, 256, 0, stream>>>(
        x, pay, offsets, counts, wbf, rootw, bias, out);
}

// Round 6
// 311.142 us; speedup vs baseline: 4.6928x; 1.3119x over previous
//
#include <hip/hip_runtime.h>
#include <hip/hip_bf16.h>

// SplineConv (degree-1 B-spline, DIM=2, K=5, open), N=100000, E=1600000, 32->32.
// R13: R12 confirmed the LDS-atomic theory (conv 1100->139us with plain RMW).
//      Remaining 408us = conv 139 + ~270 aux (unchanged since R7). Aux model:
//      3.2M global atomics (hist 1.6M + scatter 1.6M w/ return) at ~35 G/s
//      ~= 100us, plus scatter's scattered writes, 6 launches, and scan2's
//      1-block device-wide serialization. R13:
//      - hist's atomic RETURN VALUE is the edge's per-row rank -> store
//        rank[e] (u16); scatter becomes atomic-free pack: pos =
//        offsets[row] + rank[e]. Halves global atomics.
//      - scan2 folded into scan3 (each block computes the 98-wide blksum
//        prefix itself in LDS, parallel across blocks). One fewer launch +
//        no 1-block device-wide stall.
//      - wconv fused into hist (25 extra blocks). One fewer launch.
//      conv_kernel unchanged from verified R12.

#define NN   100000
#define EE   1600000
#define KTOT 25

#define ROWS_PB 16
#define NBLK    (NN / ROWS_PB)        // 6250 exact, no tail
#define HP      33                    // dword pitch per k-slot (132 bytes)
#define HROW    (KTOT * HP)           // 825 dwords per row

// ws layout (int32 units): counts | offsets | blksum | wbf | rank | pay
#define WS_COUNTS  0                  // 100000
#define WS_OFFSETS 100000             // 100000
#define WS_BLKSUM  200000             // 128
#define WS_WBF     200128             // 12800 (25600 bf16)
#define WS_RANK    212928             // 800000 (1.6M u16)
#define WS_PAY     1012928            // 3200000 (1.6M uint2); byte off 16-aligned
#define SCAN_NBLK  98                 // ceil(100000/1024)

typedef __attribute__((ext_vector_type(8))) short short8;
typedef __attribute__((ext_vector_type(4))) float f32x4;

// hist (blocks 0..2047): counts[row]++ and rank[e] = old value.
// wconv (blocks 2048..2072): weight fp32 -> bf16 in MFMA B-fragment order.
__global__ __launch_bounds__(256)
void hist_kernel(const int* __restrict__ eidx, const float* __restrict__ weight,
                 int* __restrict__ counts, unsigned short* __restrict__ rank,
                 unsigned short* __restrict__ wbf) {
    if (blockIdx.x >= 2048) {
        int b = blockIdx.x - 2048;            // 0..24 -> k slot
        #pragma unroll
        for (int q = 0; q < 4; ++q) {
            int idx = (b << 10) + (q << 8) + threadIdx.x;
            int r = idx & 1023;
            int i = r >> 5;                   // in-channel
            int o = r & 31;                   // out-channel
            __hip_bfloat16 wv = __float2bfloat16(weight[idx]);
            int pos = (b << 10) | ((o >> 4) << 9)
                    | ((((i >> 3) << 4) | (o & 15)) << 3) | (i & 7);
            wbf[pos] = __builtin_bit_cast(unsigned short, wv);
        }
        return;
    }
    for (int e = blockIdx.x * 256 + threadIdx.x; e < EE; e += 2048 * 256) {
        int row = eidx[e];
        rank[e] = (unsigned short)atomicAdd(&counts[row], 1);
    }
}

__global__ __launch_bounds__(1024)
void scan1_kernel(const int* __restrict__ counts, int* __restrict__ offsets,
                  int* __restrict__ blksum) {
    __shared__ int buf[2][1024];
    int tid = threadIdx.x;
    int gid = blockIdx.x * 1024 + tid;
    int v = (gid < NN) ? counts[gid] : 0;
    buf[0][tid] = v;
    __syncthreads();
    int s = 0;
    for (int off = 1; off < 1024; off <<= 1) {
        int t = buf[s][tid];
        if (tid >= off) t += buf[s][tid - off];
        buf[1 - s][tid] = t;
        s ^= 1;
        __syncthreads();
    }
    if (gid < NN) offsets[gid] = buf[s][tid] - v;      // exclusive (local)
    if (tid == 1023) blksum[blockIdx.x] = buf[s][tid]; // block total
}

// scan3: add the cross-block prefix; each block computes it locally from the
// 98 blksums staged in LDS (parallel across blocks -- no 1-block kernel).
__global__ __launch_bounds__(1024)
void scan3_kernel(int* __restrict__ offsets, const int* __restrict__ blksum) {
    __shared__ int bsum[SCAN_NBLK];
    __shared__ int pre;
    int tid = threadIdx.x;
    if (tid < SCAN_NBLK) bsum[tid] = blksum[tid];
    __syncthreads();
    if (tid == 0) {
        int a = 0;
        int b = (int)blockIdx.x;
        for (int i = 0; i < b; ++i) a += bsum[i];
        pre = a;
    }
    __syncthreads();
    int gid = blockIdx.x * 1024 + tid;
    if (gid < NN) offsets[gid] += pre;
}

// pack: atomic-free scatter. pos = offsets[row] + rank[e].
// pay[pos] = {f0,f1 u16 | col:17, ibits:8}
__global__ __launch_bounds__(256)
void pack_kernel(const int* __restrict__ eidx,
                 const float* __restrict__ pseudo,
                 const unsigned short* __restrict__ rank,
                 const int* __restrict__ offsets,
                 uint2* __restrict__ pay) {
    for (int e = blockIdx.x * 256 + threadIdx.x; e < EE; e += 2048 * 256) {
        int row = eidx[e];
        int col = eidx[EE + e];
        const float2 ps = *(const float2*)(pseudo + 2 * e);
        float p0 = ps.x * 4.0f, p1 = ps.y * 4.0f;
        float l0f = floorf(p0), l1f = floorf(p1);
        float f0 = p0 - l0f, f1 = p1 - l1f;
        int l0 = (int)l0f, l1 = (int)l1f;
        int i0a = min(max(l0, 0), 4), i0b = min(max(l0 + 1, 0), 4);
        int i1a = min(max(l1, 0), 4), i1b = min(max(l1 + 1, 0), 4);
        unsigned u0 = (unsigned)(f0 * 65536.0f); if (u0 > 65535u) u0 = 65535u;
        unsigned u1 = (unsigned)(f1 * 65536.0f); if (u1 > 65535u) u1 = 65535u;
        unsigned ib = (unsigned)(i0a | (i1a << 3) | ((i0b - i0a) << 6) | ((i1b - i1a) << 7));
        unsigned w0 = u0 | (u1 << 16);
        unsigned w1 = (unsigned)col | (ib << 17);
        int pos = offsets[row] + (int)rank[e];
        pay[pos] = make_uint2(w0, w1);
    }
}

// Plain (non-atomic) LDS read-modify-write: race-free because this lane is the
// sole writer of (row, c2..c2+1) for the whole edge phase.
__device__ __forceinline__ void do_edge_rmw(float* hp, uint2 pw, float2 xv) {
    int ib = (int)((pw.y >> 17) & 0xFFu);
    float f0 = (float)(pw.x & 0xFFFFu) * 1.52587890625e-05f;
    float f1 = (float)(pw.x >> 16)     * 1.52587890625e-05f;
    int i0a = ib & 7, i1a = (ib >> 3) & 7;
    int i0b = i0a + ((ib >> 6) & 1), i1b = i1a + ((ib >> 7) & 1);
    float g0 = 1.0f - f0, g1 = 1.0f - f1;
    // k = i0 + 5*i1  ->  dword offset k*33 = i0*33 + i1*165
    float* qa  = hp + i0a * 33;
    float* qb  = hp + i0b * 33;
    float* q00 = qa + i1a * 165;
    float* q01 = qa + i1b * 165;
    float* q10 = qb + i1a * 165;
    float* q11 = qb + i1b * 165;
    float b0 = g0 * g1, b1 = g0 * f1, b2 = f0 * g1, b3 = f0 * f1;
    q00[0] += b0 * xv.x;  q00[1] += b0 * xv.y;
    q01[0] += b1 * xv.x;  q01[1] += b1 * xv.y;
    q10[0] += b2 * xv.x;  q10[1] += b2 * xv.y;
    q11[0] += b3 * xv.x;  q11[1] += b3 * xv.y;
}

__global__ __launch_bounds__(256, 3)
void conv_kernel(const float* __restrict__ x,
                 const uint2* __restrict__ pay,
                 const int* __restrict__ offsets,
                 const int* __restrict__ counts,
                 const unsigned short* __restrict__ wbf,
                 const float* __restrict__ rootw,
                 const float* __restrict__ bias,
                 float* __restrict__ out)
{
    __shared__ float hs[ROWS_PB * HROW];        // 52800 B -> 3 blocks/CU

    const int tid = threadIdx.x;
    {
        float4 z = {0.f, 0.f, 0.f, 0.f};
        for (int i4 = tid; i4 < (ROWS_PB * HROW) / 4; i4 += 256)
            ((float4*)hs)[i4] = z;
    }
    __syncthreads();

    const int row0 = blockIdx.x * ROWS_PB;

    // ---- edge phase: one 16-lane team per row; lane owns channels c2,c2+1 ----
    {
        const int team = tid >> 4;             // 0..15 -> row
        const int l    = tid & 15;
        const int c2   = l * 2;
        const int row  = row0 + team;
        const int s    = offsets[row];
        const int e    = s + counts[row];

        float* hp = &hs[team * HROW + c2];

        int e0 = s;
        for (; e0 + 1 < e; e0 += 2) {
            uint2 pA = pay[e0];
            uint2 pB = pay[e0 + 1];
            int colA = (int)(pA.y & 0x1FFFFu);
            int colB = (int)(pB.y & 0x1FFFFu);
            float2 xA = *(const float2*)(x + colA * 32 + c2);
            float2 xB = *(const float2*)(x + colB * 32 + c2);
            do_edge_rmw(hp, pA, xA);
            do_edge_rmw(hp, pB, xB);
        }
        if (e0 < e) {
            uint2 pA = pay[e0];
            int colA = (int)(pA.y & 0x1FFFFu);
            float2 xA = *(const float2*)(x + colA * 32 + c2);
            do_edge_rmw(hp, pA, xA);
        }
    }
    __syncthreads();

    // ---- GEMM + fused epilogue: 2 waves, out16x32 = h(16x800) x W(800x32) ----
    const int wid  = tid >> 6;
    const int lane = tid & 63;
    if (wid < 2) {
        const int lrow = lane & 15;
        const int kg   = lane >> 4;
        const float* hb = &hs[lrow * HROW + kg * 8];
        const unsigned short* wp = wbf + (wid << 9) + (lane << 3);
        f32x4 acc = {0.f, 0.f, 0.f, 0.f};
        for (int k = 0; k < KTOT; ++k) {
            const float* hpk = hb + k * HP;
            short8 a;
            #pragma unroll
            for (int j = 0; j < 8; ++j) {
                __hip_bfloat16 hv = __float2bfloat16(hpk[j]);
                a[j] = __builtin_bit_cast(short, hv);
            }
            short8 b = *(const short8*)(wp + (k << 10));
            acc = __builtin_amdgcn_mfma_f32_16x16x32_bf16(a, b, acc, 0, 0, 0);
        }
        // epilogue: out = acc/deg + x@rootw + bias   (C/D: col=l&15, row=(l>>4)*4+q)
        const int ocol  = (wid << 4) | (lane & 15);
        const int rbase = row0 + ((lane >> 4) << 2);
        float rcol[32];
        #pragma unroll
        for (int i = 0; i < 32; ++i) rcol[i] = rootw[i * 32 + ocol];
        float bv = bias[ocol];
        #pragma unroll
        for (int q = 0; q < 4; ++q) {
            int row = rbase + q;
            float dg = fmaxf((float)counts[row], 1.0f);
            const float4* xr = (const float4*)(x + row * 32);
            float v = 0.f;
            #pragma unroll
            for (int m = 0; m < 8; ++m) {
                float4 xm = xr[m];
                v = fmaf(xm.x, rcol[4 * m + 0], v);
                v = fmaf(xm.y, rcol[4 * m + 1], v);
                v = fmaf(xm.z, rcol[4 * m + 2], v);
                v = fmaf(xm.w, rcol[4 * m + 3], v);
            }
            out[row * 32 + ocol] = acc[q] / dg + v + bv;
        }
    }
}

extern "C" void kernel_launch(void* const* d_in, const int* in_sizes, int n_in,
                              void* d_out, int out_size, void* d_ws, size_t ws_size,
                              hipStream_t stream) {
    const float* x      = (const float*)d_in[0];
    const int*   eidx   = (const int*)d_in[1];
    const float* pseudo = (const float*)d_in[2];
    const float* weight = (const float*)d_in[3];
    const float* rootw  = (const float*)d_in[4];
    const float* bias   = (const float*)d_in[5];
    float* out = (float*)d_out;

    int* ws      = (int*)d_ws;
    int* counts  = ws + WS_COUNTS;
    int* offsets = ws + WS_OFFSETS;
    int* blksum  = ws + WS_BLKSUM;
    unsigned short* wbf  = (unsigned short*)(ws + WS_WBF);
    unsigned short* rank = (unsigned short*)(ws + WS_RANK);
    uint2* pay   = (uint2*)(ws + WS_PAY);

    hipMemsetAsync(counts, 0, (size_t)NN * sizeof(int), stream);

    hist_kernel <<<2073, 256, 0, stream>>>(eidx, weight, counts, rank, wbf);
    scan1_kernel<<<SCAN_NBLK, 1024, 0, stream>>>(counts, offsets, blksum);
    scan3_kernel<<<SCAN_NBLK, 1024, 0, stream>>>(offsets, blksum);
    pack_kernel <<<2048, 256, 0, stream>>>(eidx, pseudo, rank, offsets, pay);

    conv_kernel<<<NBLK, 256, 0, stream>>>(
        x, pay, offsets, counts, wbf, rootw, bias, out);
}

// Round 7
// 300.501 us; speedup vs baseline: 4.8590x; 1.0354x over previous
//
#include <hip/hip_runtime.h>
#include <hip/hip_bf16.h>

// SplineConv (degree-1 B-spline, DIM=2, K=5, open), N=100000, E=1600000, 32->32.
// R14: R13 verified (311us = conv 139 + aux ~172). conv is VALU+latency bound
//      (VALUBusy 31%, DS ~15us, HBM 9%): per-edge decode (u16 dequant, frac,
//      clamp, 6 addr calcs ~40 lane-ops) dominates and is redone 1.6M times in
//      conv although pack already touches every edge. R14:
//      - pack PRECOMPUTES the basis: payload = 16B {b0,b1,b2 fp32 |
//        col:17,k0:5,d0:1,d1:1}. conv decode = b3=1-b0-b1-b2 (basis partitions
//        unity) + 3 bfe + 4 addr adds ~= 21 lane-ops/edge (0.5x), and kills
//        the u16 quantization round-trip (better precision than baseline).
//      - edge loop unroll-4 with all 8 loads (4 pay + 4 x) issued up front:
//        8 VMEM in flight/wave covers the x-gather L2 latency.
//      conv GEMM phase + aux structure unchanged from verified R13.

#define NN   100000
#define EE   1600000
#define KTOT 25

#define ROWS_PB 16
#define NBLK    (NN / ROWS_PB)        // 6250 exact, no tail
#define HP      33                    // dword pitch per k-slot (132 bytes)
#define HROW    (KTOT * HP)           // 825 dwords per row

// ws layout (int32 units): counts | offsets | blksum | wbf | rank | pay
#define WS_COUNTS  0                  // 100000
#define WS_OFFSETS 100000             // 100000
#define WS_BLKSUM  200000             // 128
#define WS_WBF     200128             // 12800 (25600 bf16)
#define WS_RANK    212928             // 800000 (1.6M u16)
#define WS_PAY     1012928            // 6400000 (1.6M uint4, 16B-aligned byte off)
#define SCAN_NBLK  98                 // ceil(100000/1024)

typedef __attribute__((ext_vector_type(8))) short short8;
typedef __attribute__((ext_vector_type(4))) float f32x4;

// hist (blocks 0..2047): counts[row]++ and rank[e] = old value.
// wconv (blocks 2048..2072): weight fp32 -> bf16 in MFMA B-fragment order.
__global__ __launch_bounds__(256)
void hist_kernel(const int* __restrict__ eidx, const float* __restrict__ weight,
                 int* __restrict__ counts, unsigned short* __restrict__ rank,
                 unsigned short* __restrict__ wbf) {
    if (blockIdx.x >= 2048) {
        int b = blockIdx.x - 2048;            // 0..24 -> k slot
        #pragma unroll
        for (int q = 0; q < 4; ++q) {
            int idx = (b << 10) + (q << 8) + threadIdx.x;
            int r = idx & 1023;
            int i = r >> 5;                   // in-channel
            int o = r & 31;                   // out-channel
            __hip_bfloat16 wv = __float2bfloat16(weight[idx]);
            int pos = (b << 10) | ((o >> 4) << 9)
                    | ((((i >> 3) << 4) | (o & 15)) << 3) | (i & 7);
            wbf[pos] = __builtin_bit_cast(unsigned short, wv);
        }
        return;
    }
    for (int e = blockIdx.x * 256 + threadIdx.x; e < EE; e += 2048 * 256) {
        int row = eidx[e];
        rank[e] = (unsigned short)atomicAdd(&counts[row], 1);
    }
}

__global__ __launch_bounds__(1024)
void scan1_kernel(const int* __restrict__ counts, int* __restrict__ offsets,
                  int* __restrict__ blksum) {
    __shared__ int buf[2][1024];
    int tid = threadIdx.x;
    int gid = blockIdx.x * 1024 + tid;
    int v = (gid < NN) ? counts[gid] : 0;
    buf[0][tid] = v;
    __syncthreads();
    int s = 0;
    for (int off = 1; off < 1024; off <<= 1) {
        int t = buf[s][tid];
        if (tid >= off) t += buf[s][tid - off];
        buf[1 - s][tid] = t;
        s ^= 1;
        __syncthreads();
    }
    if (gid < NN) offsets[gid] = buf[s][tid] - v;      // exclusive (local)
    if (tid == 1023) blksum[blockIdx.x] = buf[s][tid]; // block total
}

// scan3: add the cross-block prefix; each block computes it locally from the
// 98 blksums staged in LDS (parallel across blocks -- no 1-block kernel).
__global__ __launch_bounds__(1024)
void scan3_kernel(int* __restrict__ offsets, const int* __restrict__ blksum) {
    __shared__ int bsum[SCAN_NBLK];
    __shared__ int pre;
    int tid = threadIdx.x;
    if (tid < SCAN_NBLK) bsum[tid] = blksum[tid];
    __syncthreads();
    if (tid == 0) {
        int a = 0;
        int b = (int)blockIdx.x;
        for (int i = 0; i < b; ++i) a += bsum[i];
        pre = a;
    }
    __syncthreads();
    int gid = blockIdx.x * 1024 + tid;
    if (gid < NN) offsets[gid] += pre;
}

// pack: atomic-free scatter with PRECOMPUTED basis.
// pay[pos] = {b0 fp32, b1 fp32, b2 fp32, col:17 | k0:5<<17 | d0:1<<22 | d1:1<<23}
// where b3 = 1 - b0 - b1 - b2 (degree-1 tensor basis partitions unity).
__global__ __launch_bounds__(256)
void pack_kernel(const int* __restrict__ eidx,
                 const float* __restrict__ pseudo,
                 const unsigned short* __restrict__ rank,
                 const int* __restrict__ offsets,
                 uint4* __restrict__ pay) {
    for (int e = blockIdx.x * 256 + threadIdx.x; e < EE; e += 2048 * 256) {
        int row = eidx[e];
        int col = eidx[EE + e];
        const float2 ps = *(const float2*)(pseudo + 2 * e);
        float p0 = ps.x * 4.0f, p1 = ps.y * 4.0f;
        float l0f = floorf(p0), l1f = floorf(p1);
        float f0 = p0 - l0f, f1 = p1 - l1f;
        int l0 = (int)l0f, l1 = (int)l1f;
        int i0a = min(max(l0, 0), 4), i0b = min(max(l0 + 1, 0), 4);
        int i1a = min(max(l1, 0), 4), i1b = min(max(l1 + 1, 0), 4);
        float g0 = 1.0f - f0, g1 = 1.0f - f1;
        float b0 = g0 * g1;            // (i0a, i1a)
        float b1 = g0 * f1;            // (i0a, i1b)
        float b2 = f0 * g1;            // (i0b, i1a)
        int k0 = i0a + 5 * i1a;
        int d0 = i0b - i0a;
        int d1 = i1b - i1a;
        unsigned w = (unsigned)col | ((unsigned)k0 << 17)
                   | ((unsigned)d0 << 22) | ((unsigned)d1 << 23);
        int pos = offsets[row] + (int)rank[e];
        pay[pos] = make_uint4(__builtin_bit_cast(unsigned, b0),
                              __builtin_bit_cast(unsigned, b1),
                              __builtin_bit_cast(unsigned, b2), w);
    }
}

// Plain (non-atomic) LDS read-modify-write: race-free because this lane is the
// sole writer of (row, c2..c2+1) for the whole edge phase.
__device__ __forceinline__ void do_edge_rmw(float* hp, uint4 pw, float2 xv) {
    float b0 = __builtin_bit_cast(float, pw.x);
    float b1 = __builtin_bit_cast(float, pw.y);
    float b2 = __builtin_bit_cast(float, pw.z);
    float b3 = 1.0f - b0 - b1 - b2;
    unsigned km = pw.w >> 17;
    int k0 = (int)(km & 31u);
    int d0 = (int)((km >> 5) & 1u);
    int d1 = (int)((km >> 6) & 1u);
    int o1 = d1 * 165;                 // 5 slots * 33 dwords
    float* q00 = hp + k0 * 33;         // (i0a, i1a)
    float* q10 = q00 + d0 * 33;        // (i0b, i1a)
    float* q01 = q00 + o1;             // (i0a, i1b)
    float* q11 = q10 + o1;             // (i0b, i1b)
    q00[0] += b0 * xv.x;  q00[1] += b0 * xv.y;
    q01[0] += b1 * xv.x;  q01[1] += b1 * xv.y;
    q10[0] += b2 * xv.x;  q10[1] += b2 * xv.y;
    q11[0] += b3 * xv.x;  q11[1] += b3 * xv.y;
}

__global__ __launch_bounds__(256, 3)
void conv_kernel(const float* __restrict__ x,
                 const uint4* __restrict__ pay,
                 const int* __restrict__ offsets,
                 const int* __restrict__ counts,
                 const unsigned short* __restrict__ wbf,
                 const float* __restrict__ rootw,
                 const float* __restrict__ bias,
                 float* __restrict__ out)
{
    __shared__ float hs[ROWS_PB * HROW];        // 52800 B -> 3 blocks/CU

    const int tid = threadIdx.x;
    {
        float4 z = {0.f, 0.f, 0.f, 0.f};
        for (int i4 = tid; i4 < (ROWS_PB * HROW) / 4; i4 += 256)
            ((float4*)hs)[i4] = z;
    }
    __syncthreads();

    const int row0 = blockIdx.x * ROWS_PB;

    // ---- edge phase: one 16-lane team per row; lane owns channels c2,c2+1 ----
    {
        const int team = tid >> 4;             // 0..15 -> row
        const int l    = tid & 15;
        const int c2   = l * 2;
        const int row  = row0 + team;
        const int s    = offsets[row];
        const int e    = s + counts[row];

        float* hp = &hs[team * HROW + c2];

        int e0 = s;
        for (; e0 + 3 < e; e0 += 4) {
            uint4 p0 = pay[e0];
            uint4 p1 = pay[e0 + 1];
            uint4 p2 = pay[e0 + 2];
            uint4 p3 = pay[e0 + 3];
            float2 x0 = *(const float2*)(x + (p0.w & 0x1FFFFu) * 32 + c2);
            float2 x1 = *(const float2*)(x + (p1.w & 0x1FFFFu) * 32 + c2);
            float2 x2 = *(const float2*)(x + (p2.w & 0x1FFFFu) * 32 + c2);
            float2 x3 = *(const float2*)(x + (p3.w & 0x1FFFFu) * 32 + c2);
            do_edge_rmw(hp, p0, x0);
            do_edge_rmw(hp, p1, x1);
            do_edge_rmw(hp, p2, x2);
            do_edge_rmw(hp, p3, x3);
        }
        for (; e0 < e; ++e0) {
            uint4 p = pay[e0];
            float2 xv = *(const float2*)(x + (p.w & 0x1FFFFu) * 32 + c2);
            do_edge_rmw(hp, p, xv);
        }
    }
    __syncthreads();

    // ---- GEMM + fused epilogue: 2 waves, out16x32 = h(16x800) x W(800x32) ----
    const int wid  = tid >> 6;
    const int lane = tid & 63;
    if (wid < 2) {
        const int lrow = lane & 15;
        const int kg   = lane >> 4;
        const float* hb = &hs[lrow * HROW + kg * 8];
        const unsigned short* wp = wbf + (wid << 9) + (lane << 3);
        f32x4 acc = {0.f, 0.f, 0.f, 0.f};
        for (int k = 0; k < KTOT; ++k) {
            const float* hpk = hb + k * HP;
            short8 a;
            #pragma unroll
            for (int j = 0; j < 8; ++j) {
                __hip_bfloat16 hv = __float2bfloat16(hpk[j]);
                a[j] = __builtin_bit_cast(short, hv);
            }
            short8 b = *(const short8*)(wp + (k << 10));
            acc = __builtin_amdgcn_mfma_f32_16x16x32_bf16(a, b, acc, 0, 0, 0);
        }
        // epilogue: out = acc/deg + x@rootw + bias   (C/D: col=l&15, row=(l>>4)*4+q)
        const int ocol  = (wid << 4) | (lane & 15);
        const int rbase = row0 + ((lane >> 4) << 2);
        float rcol[32];
        #pragma unroll
        for (int i = 0; i < 32; ++i) rcol[i] = rootw[i * 32 + ocol];
        float bv = bias[ocol];
        #pragma unroll
        for (int q = 0; q < 4; ++q) {
            int row = rbase + q;
            float dg = fmaxf((float)counts[row], 1.0f);
            const float4* xr = (const float4*)(x + row * 32);
            float v = 0.f;
            #pragma unroll
            for (int m = 0; m < 8; ++m) {
                float4 xm = xr[m];
                v = fmaf(xm.x, rcol[4 * m + 0], v);
                v = fmaf(xm.y, rcol[4 * m + 1], v);
                v = fmaf(xm.z, rcol[4 * m + 2], v);
                v = fmaf(xm.w, rcol[4 * m + 3], v);
            }
            out[row * 32 + ocol] = acc[q] / dg + v + bv;
        }
    }
}

extern "C" void kernel_launch(void* const* d_in, const int* in_sizes, int n_in,
                              void* d_out, int out_size, void* d_ws, size_t ws_size,
                              hipStream_t stream) {
    const float* x      = (const float*)d_in[0];
    const int*   eidx   = (const int*)d_in[1];
    const float* pseudo = (const float*)d_in[2];
    const float* weight = (const float*)d_in[3];
    const float* rootw  = (const float*)d_in[4];
    const float* bias   = (const float*)d_in[5];
    float* out = (float*)d_out;

    int* ws      = (int*)d_ws;
    int* counts  = ws + WS_COUNTS;
    int* offsets = ws + WS_OFFSETS;
    int* blksum  = ws + WS_BLKSUM;
    unsigned short* wbf  = (unsigned short*)(ws + WS_WBF);
    unsigned short* rank = (unsigned short*)(ws + WS_RANK);
    uint4* pay   = (uint4*)(ws + WS_PAY);

    hipMemsetAsync(counts, 0, (size_t)NN * sizeof(int), stream);

    hist_kernel <<<2073, 256, 0, stream>>>(eidx, weight, counts, rank, wbf);
    scan1_kernel<<<SCAN_NBLK, 1024, 0, stream>>>(counts, offsets, blksum);
    scan3_kernel<<<SCAN_NBLK, 1024, 0, stream>>>(offsets, blksum);
    pack_kernel <<<2048, 256, 0, stream>>>(eidx, pseudo, rank, offsets, pay);

    conv_kernel<<<NBLK, 256, 0, stream>>>(
        x, pay, offsets, counts, wbf, rootw, bias, out);
}

// Round 8
// 292.968 us; speedup vs baseline: 4.9839x; 1.0257x over previous
//
#include <hip/hip_runtime.h>
#include <hip/hip_bf16.h>

// SplineConv (degree-1 B-spline, DIM=2, K=5, open), N=100000, E=1600000, 32->32.
// R15: R14 showed conv is DS-PIPE bound, not VALU (VALUBusy fell 31->26% while
//      dur fell only 10%). Model: 8 scalar b32 RMW/lane/edge, unmergeable to
//      b64 because row pitch 825 dwords is ODD -> 25K DS wave-instrs/CU x 5.8cy
//      ~= 60us + 17us conflicts on the ONE per-CU DS pipe (~77 of 125us).
//      Fix: layout hs[k][row*32 + (c ^ ((row&7)<<2))], K-stride 512 dwords:
//      - even 8B-aligned lane bases -> RMW = 4 ds_read_b64 + 4 ds_write_b64
//        (half the instrs, bytes = BW floor). LDS 52.8->51.2KB, 3 blocks/CU.
//      - intra-row XOR swizzle keeps GEMM A-frag b128 reads 2-way (not 16-way);
//        swizzle folded into two per-lane base pointers (zero per-k cost).
//      - batched float2 RMW safe: pseudo in [0,1) => d0=d1=1 (no slot alias).
//      Aux chain unchanged from R13/R14 (attribution).

#define NN   100000
#define EE   1600000
#define KTOT 25

#define ROWS_PB 16
#define NBLK    (NN / ROWS_PB)        // 6250 exact, no tail
#define KS      512                   // dword stride per k-slot: [k][row*32+c^]

// ws layout (int32 units): counts | offsets | blksum | wbf | rank | pay
#define WS_COUNTS  0                  // 100000
#define WS_OFFSETS 100000             // 100000
#define WS_BLKSUM  200000             // 128
#define WS_WBF     200128             // 12800 (25600 bf16)
#define WS_RANK    212928             // 800000 (1.6M u16)
#define WS_PAY     1012928            // 6400000 (1.6M uint4, 16B-aligned byte off)
#define SCAN_NBLK  98                 // ceil(100000/1024)

typedef __attribute__((ext_vector_type(8))) short short8;
typedef __attribute__((ext_vector_type(4))) float f32x4;

// hist (blocks 0..2047): counts[row]++ and rank[e] = old value.
// wconv (blocks 2048..2072): weight fp32 -> bf16 in MFMA B-fragment order.
__global__ __launch_bounds__(256)
void hist_kernel(const int* __restrict__ eidx, const float* __restrict__ weight,
                 int* __restrict__ counts, unsigned short* __restrict__ rank,
                 unsigned short* __restrict__ wbf) {
    if (blockIdx.x >= 2048) {
        int b = blockIdx.x - 2048;            // 0..24 -> k slot
        #pragma unroll
        for (int q = 0; q < 4; ++q) {
            int idx = (b << 10) + (q << 8) + threadIdx.x;
            int r = idx & 1023;
            int i = r >> 5;                   // in-channel
            int o = r & 31;                   // out-channel
            __hip_bfloat16 wv = __float2bfloat16(weight[idx]);
            int pos = (b << 10) | ((o >> 4) << 9)
                    | ((((i >> 3) << 4) | (o & 15)) << 3) | (i & 7);
            wbf[pos] = __builtin_bit_cast(unsigned short, wv);
        }
        return;
    }
    for (int e = blockIdx.x * 256 + threadIdx.x; e < EE; e += 2048 * 256) {
        int row = eidx[e];
        rank[e] = (unsigned short)atomicAdd(&counts[row], 1);
    }
}

__global__ __launch_bounds__(1024)
void scan1_kernel(const int* __restrict__ counts, int* __restrict__ offsets,
                  int* __restrict__ blksum) {
    __shared__ int buf[2][1024];
    int tid = threadIdx.x;
    int gid = blockIdx.x * 1024 + tid;
    int v = (gid < NN) ? counts[gid] : 0;
    buf[0][tid] = v;
    __syncthreads();
    int s = 0;
    for (int off = 1; off < 1024; off <<= 1) {
        int t = buf[s][tid];
        if (tid >= off) t += buf[s][tid - off];
        buf[1 - s][tid] = t;
        s ^= 1;
        __syncthreads();
    }
    if (gid < NN) offsets[gid] = buf[s][tid] - v;      // exclusive (local)
    if (tid == 1023) blksum[blockIdx.x] = buf[s][tid]; // block total
}

// scan3: add the cross-block prefix; each block computes it locally from the
// 98 blksums staged in LDS (parallel across blocks -- no 1-block kernel).
__global__ __launch_bounds__(1024)
void scan3_kernel(int* __restrict__ offsets, const int* __restrict__ blksum) {
    __shared__ int bsum[SCAN_NBLK];
    __shared__ int pre;
    int tid = threadIdx.x;
    if (tid < SCAN_NBLK) bsum[tid] = blksum[tid];
    __syncthreads();
    if (tid == 0) {
        int a = 0;
        int b = (int)blockIdx.x;
        for (int i = 0; i < b; ++i) a += bsum[i];
        pre = a;
    }
    __syncthreads();
    int gid = blockIdx.x * 1024 + tid;
    if (gid < NN) offsets[gid] += pre;
}

// pack: atomic-free scatter with PRECOMPUTED basis.
// pay[pos] = {b0 fp32, b1 fp32, b2 fp32, col:17 | k0:5<<17 | d0:1<<22 | d1:1<<23}
// where b3 = 1 - b0 - b1 - b2 (degree-1 tensor basis partitions unity).
__global__ __launch_bounds__(256)
void pack_kernel(const int* __restrict__ eidx,
                 const float* __restrict__ pseudo,
                 const unsigned short* __restrict__ rank,
                 const int* __restrict__ offsets,
                 uint4* __restrict__ pay) {
    for (int e = blockIdx.x * 256 + threadIdx.x; e < EE; e += 2048 * 256) {
        int row = eidx[e];
        int col = eidx[EE + e];
        const float2 ps = *(const float2*)(pseudo + 2 * e);
        float p0 = ps.x * 4.0f, p1 = ps.y * 4.0f;
        float l0f = floorf(p0), l1f = floorf(p1);
        float f0 = p0 - l0f, f1 = p1 - l1f;
        int l0 = (int)l0f, l1 = (int)l1f;
        int i0a = min(max(l0, 0), 4), i0b = min(max(l0 + 1, 0), 4);
        int i1a = min(max(l1, 0), 4), i1b = min(max(l1 + 1, 0), 4);
        float g0 = 1.0f - f0, g1 = 1.0f - f1;
        float b0 = g0 * g1;            // (i0a, i1a)
        float b1 = g0 * f1;            // (i0a, i1b)
        float b2 = f0 * g1;            // (i0b, i1a)
        int k0 = i0a + 5 * i1a;
        int d0 = i0b - i0a;
        int d1 = i1b - i1a;
        unsigned w = (unsigned)col | ((unsigned)k0 << 17)
                   | ((unsigned)d0 << 22) | ((unsigned)d1 << 23);
        int pos = offsets[row] + (int)rank[e];
        pay[pos] = make_uint4(__builtin_bit_cast(unsigned, b0),
                              __builtin_bit_cast(unsigned, b1),
                              __builtin_bit_cast(unsigned, b2), w);
    }
}

// Plain (non-atomic) LDS RMW as float2 (ds_read_b64/ds_write_b64): race-free
// (single-writer per (row,c-pair)); alias-free (d0=d1=1 since pseudo<1.0).
__device__ __forceinline__ void do_edge_rmw(float* hp, uint4 pw, float2 xv) {
    float b0 = __builtin_bit_cast(float, pw.x);
    float b1 = __builtin_bit_cast(float, pw.y);
    float b2 = __builtin_bit_cast(float, pw.z);
    float b3 = 1.0f - b0 - b1 - b2;
    unsigned km = pw.w >> 17;
    int k0 = (int)(km & 31u);
    int d0 = (int)((km >> 5) & 1u);
    int d1 = (int)((km >> 6) & 1u);
    float2* q00 = (float2*)(hp + (k0 << 9));
    float2* q10 = (float2*)(hp + ((k0 + d0) << 9));
    float2* q01 = (float2*)(hp + ((k0 + 5 * d1) << 9));
    float2* q11 = (float2*)(hp + ((k0 + d0 + 5 * d1) << 9));
    float2 v00 = *q00, v01 = *q01, v10 = *q10, v11 = *q11;
    v00.x += b0 * xv.x;  v00.y += b0 * xv.y;
    v01.x += b1 * xv.x;  v01.y += b1 * xv.y;
    v10.x += b2 * xv.x;  v10.y += b2 * xv.y;
    v11.x += b3 * xv.x;  v11.y += b3 * xv.y;
    *q00 = v00;  *q01 = v01;  *q10 = v10;  *q11 = v11;
}

__global__ __launch_bounds__(256, 3)
void conv_kernel(const float* __restrict__ x,
                 const uint4* __restrict__ pay,
                 const int* __restrict__ offsets,
                 const int* __restrict__ counts,
                 const unsigned short* __restrict__ wbf,
                 const float* __restrict__ rootw,
                 const float* __restrict__ bias,
                 float* __restrict__ out)
{
    __shared__ float hs[KTOT * KS];             // 51200 B -> 3 blocks/CU

    const int tid = threadIdx.x;
    {
        float4 z = {0.f, 0.f, 0.f, 0.f};
        for (int i4 = tid; i4 < (KTOT * KS) / 4; i4 += 256)
            ((float4*)hs)[i4] = z;
    }
    __syncthreads();

    const int row0 = blockIdx.x * ROWS_PB;

    // ---- edge phase: one 16-lane team per row; lane owns channels c2,c2+1 ----
    {
        const int team = tid >> 4;             // 0..15 -> row
        const int l    = tid & 15;
        const int c2   = l * 2;
        const int row  = row0 + team;
        const int s    = offsets[row];
        const int e    = s + counts[row];

        // lane base: row segment + XOR-swizzled channel offset (8B aligned)
        float* hp = &hs[team * 32 + (c2 ^ ((team & 7) << 2))];

        int e0 = s;
        for (; e0 + 3 < e; e0 += 4) {
            uint4 p0 = pay[e0];
            uint4 p1 = pay[e0 + 1];
            uint4 p2 = pay[e0 + 2];
            uint4 p3 = pay[e0 + 3];
            float2 x0 = *(const float2*)(x + (p0.w & 0x1FFFFu) * 32 + c2);
            float2 x1 = *(const float2*)(x + (p1.w & 0x1FFFFu) * 32 + c2);
            float2 x2 = *(const float2*)(x + (p2.w & 0x1FFFFu) * 32 + c2);
            float2 x3 = *(const float2*)(x + (p3.w & 0x1FFFFu) * 32 + c2);
            do_edge_rmw(hp, p0, x0);
            do_edge_rmw(hp, p1, x1);
            do_edge_rmw(hp, p2, x2);
            do_edge_rmw(hp, p3, x3);
        }
        for (; e0 < e; ++e0) {
            uint4 p = pay[e0];
            float2 xv = *(const float2*)(x + (p.w & 0x1FFFFu) * 32 + c2);
            do_edge_rmw(hp, p, xv);
        }
    }
    __syncthreads();

    // ---- GEMM + fused epilogue: 2 waves, out16x32 = h(16x800) x W(800x32) ----
    const int wid  = tid >> 6;
    const int lane = tid & 63;
    if (wid < 2) {
        const int lrow = lane & 15;
        const int kg   = lane >> 4;
        // undo the intra-row swizzle: s = (lrow&7)<<2; logical j 0..3 live at
        // B+s4, logical j 4..7 at B+(4-s4), where B = (kg*8)^(s&24).
        const int s    = (lrow & 7) << 2;
        const int s4   = s & 4;
        const int B    = (kg * 8) ^ (s & 24);
        const float* p0 = hs + lrow * 32 + B + s4;
        const float* p1 = hs + lrow * 32 + B + (4 - s4);
        const unsigned short* wp = wbf + (wid << 9) + (lane << 3);
        f32x4 acc = {0.f, 0.f, 0.f, 0.f};
        for (int k = 0; k < KTOT; ++k) {
            float4 lo = *(const float4*)(p0 + (k << 9));
            float4 hi = *(const float4*)(p1 + (k << 9));
            short8 a;
            a[0] = __builtin_bit_cast(short, (__hip_bfloat16)__float2bfloat16(lo.x));
            a[1] = __builtin_bit_cast(short, (__hip_bfloat16)__float2bfloat16(lo.y));
            a[2] = __builtin_bit_cast(short, (__hip_bfloat16)__float2bfloat16(lo.z));
            a[3] = __builtin_bit_cast(short, (__hip_bfloat16)__float2bfloat16(lo.w));
            a[4] = __builtin_bit_cast(short, (__hip_bfloat16)__float2bfloat16(hi.x));
            a[5] = __builtin_bit_cast(short, (__hip_bfloat16)__float2bfloat16(hi.y));
            a[6] = __builtin_bit_cast(short, (__hip_bfloat16)__float2bfloat16(hi.z));
            a[7] = __builtin_bit_cast(short, (__hip_bfloat16)__float2bfloat16(hi.w));
            short8 b = *(const short8*)(wp + (k << 10));
            acc = __builtin_amdgcn_mfma_f32_16x16x32_bf16(a, b, acc, 0, 0, 0);
        }
        // epilogue: out = acc/deg + x@rootw + bias   (C/D: col=l&15, row=(l>>4)*4+q)
        const int ocol  = (wid << 4) | (lane & 15);
        const int rbase = row0 + ((lane >> 4) << 2);
        float rcol[32];
        #pragma unroll
        for (int i = 0; i < 32; ++i) rcol[i] = rootw[i * 32 + ocol];
        float bv = bias[ocol];
        #pragma unroll
        for (int q = 0; q < 4; ++q) {
            int row = rbase + q;
            float dg = fmaxf((float)counts[row], 1.0f);
            const float4* xr = (const float4*)(x + row * 32);
            float v = 0.f;
            #pragma unroll
            for (int m = 0; m < 8; ++m) {
                float4 xm = xr[m];
                v = fmaf(xm.x, rcol[4 * m + 0], v);
                v = fmaf(xm.y, rcol[4 * m + 1], v);
                v = fmaf(xm.z, rcol[4 * m + 2], v);
                v = fmaf(xm.w, rcol[4 * m + 3], v);
            }
            out[row * 32 + ocol] = acc[q] / dg + v + bv;
        }
    }
}

extern "C" void kernel_launch(void* const* d_in, const int* in_sizes, int n_in,
                              void* d_out, int out_size, void* d_ws, size_t ws_size,
                              hipStream_t stream) {
    const float* x      = (const float*)d_in[0];
    const int*   eidx   = (const int*)d_in[1];
    const float* pseudo = (const float*)d_in[2];
    const float* weight = (const float*)d_in[3];
    const float* rootw  = (const float*)d_in[4];
    const float* bias   = (const float*)d_in[5];
    float* out = (float*)d_out;

    int* ws      = (int*)d_ws;
    int* counts  = ws + WS_COUNTS;
    int* offsets = ws + WS_OFFSETS;
    int* blksum  = ws + WS_BLKSUM;
    unsigned short* wbf  = (unsigned short*)(ws + WS_WBF);
    unsigned short* rank = (unsigned short*)(ws + WS_RANK);
    uint4* pay   = (uint4*)(ws + WS_PAY);

    hipMemsetAsync(counts, 0, (size_t)NN * sizeof(int), stream);

    hist_kernel <<<2073, 256, 0, stream>>>(eidx, weight, counts, rank, wbf);
    scan1_kernel<<<SCAN_NBLK, 1024, 0, stream>>>(counts, offsets, blksum);
    scan3_kernel<<<SCAN_NBLK, 1024, 0, stream>>>(offsets, blksum);
    pack_kernel <<<2048, 256, 0, stream>>>(eidx, pseudo, rank, offsets, pay);

    conv_kernel<<<NBLK, 256, 0, stream>>>(
        x, pay, offsets, counts, wbf, rootw, bias, out);
}